// Round 3
// baseline (693.689 us; speedup 1.0000x reference)
//
#include <hip/hip_runtime.h>
#include <hip/hip_bf16.h>
#include <math.h>

typedef unsigned long long u64;
typedef unsigned int u32;

#define A_TOTAL 24564
#define NCLS 80
#define NIMG 4
#define NPRE 2000
#define NLV 7
#define HBUCKETS 1024
#define BEXP_BASE 0x3CA3

__device__ __constant__ int c_klv[NLV] = {1000,1000,1000,1000,1000,1000,320};

// ---- workspace layout (bytes) ----
#define WS_HIST      0          // 28*1024*4 = 114688
#define WS_MCOUNT    114688     // 28*4
#define WS_BCOUNT    114800     // 28*4
#define WS_ZERO_END  114912
#define WS_CUTS      114912     // 28*8 (written every call by k_cuts)
#define WS_MAIN      115136     // 28*1024*8
#define WS_BND       344512     // 28*4096*8
#define WS_BOXES     1326016    // 4*2000*16
#define WS_CLS       1454016    // 4*2000*4
#define WS_SCORE     1486016    // 4*2000*4
#define WS_MASK      1518016    // 4*2000*32*8 = 2048000 (dead until k_mask)
#define WS_M         1518016    // 98256*4 (overlaps mask; dead after k_emit)
#define WS_RT        1911232    // 98256*4

__device__ inline u64 shfl_u64(u64 v, int src) {
  int lo = __shfl((int)(u32)(v & 0xFFFFFFFFULL), src);
  int hi = __shfl((int)(u32)(v >> 32), src);
  return ((u64)(u32)hi << 32) | (u32)lo;
}

__device__ inline int score_bucket(u32 bits) {
  int b = (int)(bits >> 16) - BEXP_BASE;
  return b < 0 ? 0 : (b > HBUCKETS - 1 ? HBUCKETS - 1 : b);
}

__device__ inline int level_of(int a) {
  return (a < 16384) ? 0 : (a < 22528) ? 1 : (a < 24064) ? 2 :
         (a < 24448) ? 3 : (a < 24544) ? 4 : (a < 24560) ? 5 : 6;
}

// One full wave finds (cut bucket, count-in-bucket) for top-k over a 1024-bin
// histogram h. Deterministic: same h,k -> same result.
__device__ inline void wave_find_cut(const u32* __restrict__ h, int k, int lane,
                                     int& cx, int& cy) {
  u32 s = 0;
#pragma unroll
  for (int i = 0; i < 16; ++i) s += h[lane * 16 + i];
  u32 S = s;  // inclusive suffix-sum across lanes
#pragma unroll
  for (int o = 1; o < 64; o <<= 1) {
    u32 t = (u32)__shfl_down((int)S, o);
    if (lane + o < 64) S += t;
  }
  u32 total = (u32)__shfl((int)S, 0);
  if (total <= (u32)k) { cx = -1; cy = 0; return; }
  u64 bm = __ballot(S >= (u32)k);
  int L0 = 63 - (int)__clzll((long long)bm);
  u32 Sup = (u32)__shfl_down((int)S, 1);
  if (lane == 63) Sup = 0;
  int rcx = 0, rcy = 0;
  if (lane == L0) {
    u32 cum = Sup;
    for (int i = 15; i >= 0; --i) {
      u32 c = h[lane * 16 + i];
      if (cum + c >= (u32)k) { rcx = lane * 16 + i; rcy = k - (int)cum; break; }
      cum += c;
    }
  }
  cx = __shfl(rcx, L0);
  cy = __shfl(rcy, L0);
}

// Pass 1: thread-per-anchor softmax (no cross-lane ops). Stores (m, 1/t) so
// pass 2 reproduces identical score bits; builds per-seg score histogram.
__global__ __launch_bounds__(256) void k_score(const float* __restrict__ logits,
                                               u32* __restrict__ histG,
                                               float* __restrict__ mG,
                                               float* __restrict__ rtG) {
  int g = blockIdx.x * 256 + threadIdx.x;
  if (g >= NIMG * A_TOTAL) return;
  int img = g / A_TOTAL;
  int a = g - img * A_TOTAL;
  int seg = img * NLV + level_of(a);
  const float* base = logits + (size_t)g * 81;
  float x[81];
#pragma unroll
  for (int i = 0; i < 81; ++i) x[i] = base[i];
  float m = x[0];
#pragma unroll
  for (int i = 1; i < 81; ++i) m = fmaxf(m, x[i]);
  float t = 0.f;
#pragma unroll
  for (int i = 0; i < 81; ++i) { x[i] = expf(x[i] - m); t += x[i]; }
  float rt = 1.0f / t;
  mG[g] = m;
  rtG[g] = rt;
  u32* hseg = histG + (size_t)seg * HBUCKETS;
#pragma unroll
  for (int i = 0; i < 80; ++i) {
    float s = x[i] * rt;
    if (s > 0.02f) atomicAdd(&hseg[score_bucket(__float_as_uint(s))], 1u);
  }
}

__global__ __launch_bounds__(1024) void k_cuts(const u32* __restrict__ histG,
                                               int2* __restrict__ cutsG) {
  int wid = threadIdx.x >> 6, lane = threadIdx.x & 63;
  for (int seg = wid; seg < NIMG * NLV; seg += 16) {
    int cx, cy;
    wave_find_cut(histG + (size_t)seg * HBUCKETS, c_klv[seg % NLV], lane, cx, cy);
    if (lane == 0) cutsG[seg] = make_int2(cx, cy);
  }
}

// Pass 2: recompute scores from (m, rt) (bit-identical), emit above-cut ->
// mainG, boundary-bucket -> bndG. Below-cut entries touch no atomics.
__global__ __launch_bounds__(256) void k_emit(const float* __restrict__ logits,
                                              const float* __restrict__ mG,
                                              const float* __restrict__ rtG,
                                              const int2* __restrict__ cutsG,
                                              u64* __restrict__ mainG, u32* __restrict__ mcount,
                                              u64* __restrict__ bndG, u32* __restrict__ bcount) {
  int g = blockIdx.x * 256 + threadIdx.x;
  if (g >= NIMG * A_TOTAL) return;
  int img = g / A_TOTAL;
  int a = g - img * A_TOTAL;
  int seg = img * NLV + level_of(a);
  int2 ct = cutsG[seg];
  float m = mG[g], rt = rtG[g];
  const float* base = logits + (size_t)g * 81;
#pragma unroll
  for (int i = 0; i < 80; ++i) {
    float s = expf(base[i] - m) * rt;
    if (s > 0.02f) {
      u32 bits = __float_as_uint(s);
      int bk = score_bucket(bits);
      if (bk >= ct.x) {
        u64 key = ((u64)bits << 32) | (u64)(0xFFFFFFFFu - (u32)(a * NCLS + i));
        if (ct.x < 0 || bk > ct.x) {
          u32 p = atomicAdd(&mcount[seg], 1u);
          if (p < 1024) mainG[(size_t)seg * 1024 + p] = key;
        } else {
          u32 p = atomicAdd(&bcount[seg], 1u);
          if (p < 4096) bndG[(size_t)seg * 4096 + p] = key;
        }
      }
    }
  }
}

__device__ inline void bitonic_desc(u64* s, int n) {
  for (int k = 2; k <= n; k <<= 1)
    for (int j = k >> 1; j > 0; j >>= 1) {
      __syncthreads();
      for (int i = threadIdx.x; i < n; i += blockDim.x) {
        int l = i ^ j;
        if (l > i) {
          u64 a = s[i], b = s[l];
          if (((i & k) == 0) ? (a < b) : (a > b)) { s[i] = b; s[l] = a; }
        }
      }
    }
  __syncthreads();
}

// exact per-level top-k: sort only pow2ceil(boundary count) elements
__global__ __launch_bounds__(1024) void k_refine(const u32* __restrict__ histG,
                                                 const u64* __restrict__ bndG,
                                                 const u32* __restrict__ bcount,
                                                 u64* __restrict__ mainG, u32* __restrict__ mcount) {
  int seg = blockIdx.x;
  __shared__ int sh_cx, sh_cy;
  __shared__ u64 s[4096];
  int tid = threadIdx.x, lane = tid & 63;
  if (tid < 64) {
    int cx, cy;
    wave_find_cut(histG + (size_t)seg * HBUCKETS, c_klv[seg % NLV], lane, cx, cy);
    if (lane == 0) { sh_cx = cx; sh_cy = cy; }
  }
  __syncthreads();
  if (sh_cx < 0) return;
  int m = (int)bcount[seg]; if (m > 4096) m = 4096;
  int n = 64; while (n < m) n <<= 1;
  for (int t = tid; t < n; t += 1024)
    s[t] = (t < m) ? bndG[(size_t)seg * 4096 + t] : 0ULL;
  bitonic_desc(s, n);
  int kp = sh_cy; if (kp > m) kp = m;
  int base = (int)mcount[seg];
  for (int t = tid; t < kp; t += 1024) {
    int p = base + t;
    if (p < 1024) mainG[(size_t)seg * 1024 + p] = s[t];
  }
  __syncthreads();
  if (tid == 0) {
    int nb = base + kp;
    mcount[seg] = (u32)(nb > 1024 ? 1024 : nb);
  }
}

// per-image: global cut from truncated per-level histograms, compact <2000
// above-cut, sort tiny boundary, one 2048 bitonic, decode inline.
__global__ __launch_bounds__(1024) void k_gsel(const u32* __restrict__ histG,
                                               const u64* __restrict__ mainG,
                                               const u32* __restrict__ mcount,
                                               const float4* __restrict__ priors,
                                               const float4* __restrict__ reg,
                                               float4* __restrict__ boxesG,
                                               int* __restrict__ clsG,
                                               float* __restrict__ scoreG) {
  int img = blockIdx.x;
  int tid = threadIdx.x, wid = tid >> 6, lane = tid & 63;
  __shared__ u32 H[HBUCKETS];
  __shared__ int lcx[NLV], lcy[NLV];
  __shared__ int sh_gx, sh_gy, sh_m, sh_b;
  __shared__ u64 bnd2[4096];
  __shared__ u64 sel[2048];
  if (tid == 0) { sh_m = 0; sh_b = 0; }
  if (wid < NLV) {
    int cx, cy;
    wave_find_cut(histG + (size_t)(img * NLV + wid) * HBUCKETS, c_klv[wid], lane, cx, cy);
    if (lane == 0) { lcx[wid] = cx; lcy[wid] = cy; }
  }
  __syncthreads();
  for (int b = tid; b < HBUCKETS; b += 1024) {
    u32 acc = 0;
#pragma unroll
    for (int l = 0; l < NLV; ++l) {
      u32 h = histG[(size_t)(img * NLV + l) * HBUCKETS + b];
      int cx = lcx[l];
      if (cx < 0 || b > cx) acc += h;
      else if (b == cx) acc += (u32)lcy[l];
    }
    H[b] = acc;
  }
  __syncthreads();
  if (wid == 0) {
    int gx, gy;
    wave_find_cut(H, NPRE, lane, gx, gy);
    if (lane == 0) { sh_gx = gx; sh_gy = gy; }
  }
  __syncthreads();
  int gx = sh_gx, gy = sh_gy;
  for (int l = 0; l < NLV; ++l) {
    int cnt = (int)mcount[img * NLV + l]; if (cnt > 1024) cnt = 1024;
    for (int t = tid; t < cnt; t += 1024) {
      u64 key = mainG[(size_t)(img * NLV + l) * 1024 + t];
      int b = (int)(key >> 48) - BEXP_BASE;
      b = b < 0 ? 0 : (b > HBUCKETS - 1 ? HBUCKETS - 1 : b);
      if (gx < 0 || b > gx) { int p = atomicAdd(&sh_m, 1); if (p < 2048) sel[p] = key; }
      else if (b == gx)     { int p = atomicAdd(&sh_b, 1); if (p < 4096) bnd2[p] = key; }
    }
  }
  __syncthreads();
  int msel = sh_m; if (msel > 2048) msel = 2048;
  int nb = sh_b; if (nb > 4096) nb = 4096;
  int take = 0;
  if (gx >= 0) {
    int n = 64; while (n < nb) n <<= 1;
    for (int t = tid; t < n; t += 1024) if (t >= nb) bnd2[t] = 0ULL;
    bitonic_desc(bnd2, n);
    take = gy; if (take > nb) take = nb;
    if (msel + take > 2048) take = 2048 - msel;
    for (int t = tid; t < take; t += 1024) sel[msel + t] = bnd2[t];
  }
  int tot = msel + take;
  for (int t = tid; t < 2048; t += 1024) if (t >= tot) sel[t] = 0ULL;
  bitonic_desc(sel, 2048);
  for (int t = tid; t < NPRE; t += 1024) {
    u64 key = sel[t];
    float4 bx = make_float4(0.f, 0.f, 0.f, 0.f);
    int c = -1;
    float sc = 0.f;
    if (key != 0ULL) {
      sc = __uint_as_float((u32)(key >> 32));
      u32 flat = 0xFFFFFFFFu - (u32)(key & 0xFFFFFFFFULL);
      int a = (int)(flat / NCLS);
      c = (int)(flat % NCLS);
      float4 p = priors[a];
      float4 r = reg[(size_t)img * A_TOTAL + a];
      float cx = p.x + (r.x * 0.1f) * p.z;
      float cy = p.y + (r.y * 0.1f) * p.w;
      float w = p.z * expf(r.z * 0.2f);
      float h = p.w * expf(r.w * 0.2f);
      bx.x = fminf(fmaxf(cx - w * 0.5f, 0.f), 512.f);
      bx.y = fminf(fmaxf(cy - h * 0.5f, 0.f), 512.f);
      bx.z = fminf(fmaxf(cx + w * 0.5f, 0.f), 512.f);
      bx.w = fminf(fmaxf(cy + h * 0.5f, 0.f), 512.f);
    }
    boxesG[(size_t)img * NPRE + t] = bx;
    clsG[(size_t)img * NPRE + t] = c;
    scoreG[(size_t)img * NPRE + t] = sc;
  }
}

// suppression bitmask: row i, bit j set iff j>i, same class, IoU>0.45
__global__ __launch_bounds__(256) void k_mask(const float4* __restrict__ boxesG,
                                              const int* __restrict__ clsG,
                                              u64* __restrict__ maskG) {
  __shared__ float4 lb[NPRE];
  __shared__ int lc[NPRE];
  int img = blockIdx.x / 500;
  int rb = (blockIdx.x % 500) * 4;
  for (int t = threadIdx.x; t < NPRE; t += 256) {
    lb[t] = boxesG[(size_t)img * NPRE + t];
    lc[t] = clsG[(size_t)img * NPRE + t];
  }
  __syncthreads();
  int w = threadIdx.x >> 6, lane = threadIdx.x & 63;
  int i = rb + w;
  float4 bi = lb[i];
  int ci = lc[i];
  float ai = (bi.z - bi.x) * (bi.w - bi.y);
  u64* mrow = maskG + ((size_t)img * NPRE + i) * 32;
  for (int ch = 0; ch < 32; ++ch) {
    int j = ch * 64 + lane;
    bool pred = false;
    if (j < NPRE && j > i) {
      if (lc[j] == ci) {
        float4 bj = lb[j];
        float xx1 = fmaxf(bi.x, bj.x), yy1 = fmaxf(bi.y, bj.y);
        float xx2 = fminf(bi.z, bj.z), yy2 = fminf(bi.w, bj.w);
        float ww = fmaxf(xx2 - xx1, 0.f), hh = fmaxf(yy2 - yy1, 0.f);
        float inter = ww * hh;
        float aj = (bj.z - bj.x) * (bj.w - bj.y);
        float iou = inter / fmaxf(ai + aj - inter, 1e-6f);
        pred = iou > 0.45f;
      }
    }
    u64 word = __ballot(pred);
    if (lane == 0) mrow[ch] = word;
  }
}

// greedy scan with early exit at 200 kept, fused with final gather.
__global__ __launch_bounds__(256) void k_scanfinal(const u64* __restrict__ maskG,
                                                   const float4* __restrict__ boxesG,
                                                   const int* __restrict__ clsG,
                                                   const float* __restrict__ scoreG,
                                                   float* __restrict__ out) {
  int img = blockIdx.x;
  int tid = threadIdx.x;
  __shared__ u64 sh_remv[32];
  __shared__ u32 keptList[216];
  __shared__ int sh_cnt, sh_done;
  __shared__ int kpref[257];
  __shared__ unsigned short S[NPRE];
  if (tid == 0) { sh_cnt = 0; sh_done = 0; }
  __syncthreads();
  if (tid < 64) {
    int lane = tid;
    int wl = lane & 31;
    const u64* M = maskG + (size_t)img * NPRE * 32;
    u64 remv = 0;
    u64 cur[16], nxt[16];
    int cnt = 0;
#pragma unroll
    for (int r = 0; r < 16; ++r) cur[r] = M[(size_t)r * 32 + wl];
    int t = 0;
    for (; t < 125; ++t) {
      if (t < 124) {
#pragma unroll
        for (int r = 0; r < 16; ++r) nxt[r] = M[(size_t)((t + 1) * 16 + r) * 32 + wl];
      }
#pragma unroll
      for (int r = 0; r < 16; ++r) {
        int i = t * 16 + r;
        u64 rm = shfl_u64(remv, i >> 6);
        if (!((rm >> (i & 63)) & 1ULL)) {
          remv |= cur[r];
          if (lane == 0 && cnt < 216) keptList[cnt] = (u32)i;
          ++cnt;
        }
      }
#pragma unroll
      for (int r = 0; r < 16; ++r) cur[r] = nxt[r];
      if (cnt >= 200) { ++t; break; }
    }
    if (lane == 0) sh_cnt = cnt < 216 ? cnt : 216;
    if (t >= 125) {
      if (lane == 0) sh_done = 1;
      if (lane < 32) sh_remv[lane] = remv;
    }
  }
  __syncthreads();
  int nK = sh_cnt;
  if (sh_done && nK < 200) {
    int base = tid * 8;
    bool sb[8];
    int scnt = 0;
#pragma unroll
    for (int e = 0; e < 8; ++e) {
      int i = base + e;
      bool sup = (i < NPRE) && ((sh_remv[i >> 6] >> (i & 63)) & 1ULL);
      sb[e] = sup;
      scnt += sup ? 1 : 0;
    }
    kpref[tid + 1] = scnt;
    if (tid == 0) kpref[0] = 0;
    __syncthreads();
    if (tid == 0) {
      int acc = 0;
      for (int t = 1; t <= 256; ++t) { acc += kpref[t]; kpref[t] = acc; }
    }
    __syncthreads();
    int sp = kpref[tid];
#pragma unroll
    for (int e = 0; e < 8; ++e) {
      int i = base + e;
      if (i < NPRE && sb[e]) S[sp++] = (unsigned short)i;
    }
    __syncthreads();
    if (tid < 200) {
      float fv = 0.f;
      float4 fb = make_float4(0.f, 0.f, 0.f, 0.f);
      int fc;
      if (tid < nK) {
        int idx = (int)keptList[tid];
        fv = scoreG[(size_t)img * NPRE + idx];
        fb = boxesG[(size_t)img * NPRE + idx];
        fc = clsG[(size_t)img * NPRE + idx];
      } else {
        int idx = S[tid - nK];
        fc = clsG[(size_t)img * NPRE + idx];
      }
      float* fbo = out + (size_t)img * 800 + tid * 4;
      fbo[0] = fb.x; fbo[1] = fb.y; fbo[2] = fb.z; fbo[3] = fb.w;
      out[3200 + (size_t)img * 200 + tid] = fv;
      out[4000 + (size_t)img * 200 + tid] = (float)fc;
    }
  } else {
    if (tid < 200) {
      int idx = (int)keptList[tid];
      float fv = scoreG[(size_t)img * NPRE + idx];
      float4 fb = boxesG[(size_t)img * NPRE + idx];
      int fc = clsG[(size_t)img * NPRE + idx];
      float* fbo = out + (size_t)img * 800 + tid * 4;
      fbo[0] = fb.x; fbo[1] = fb.y; fbo[2] = fb.z; fbo[3] = fb.w;
      out[3200 + (size_t)img * 200 + tid] = fv;
      out[4000 + (size_t)img * 200 + tid] = (float)fc;
    }
  }
}

extern "C" void kernel_launch(void* const* d_in, const int* in_sizes, int n_in,
                              void* d_out, int out_size, void* d_ws, size_t ws_size,
                              hipStream_t stream) {
  const float* logits = (const float*)d_in[0];
  const float4* reg = (const float4*)d_in[1];
  const float4* priors = (const float4*)d_in[2];
  char* ws = (char*)d_ws;
  u32* hist = (u32*)(ws + WS_HIST);
  u32* mcount = (u32*)(ws + WS_MCOUNT);
  u32* bcount = (u32*)(ws + WS_BCOUNT);
  int2* cuts = (int2*)(ws + WS_CUTS);
  u64* mainL = (u64*)(ws + WS_MAIN);
  u64* bndL = (u64*)(ws + WS_BND);
  float4* boxes = (float4*)(ws + WS_BOXES);
  int* cls = (int*)(ws + WS_CLS);
  float* score = (float*)(ws + WS_SCORE);
  u64* mask = (u64*)(ws + WS_MASK);
  float* mG = (float*)(ws + WS_M);
  float* rtG = (float*)(ws + WS_RT);

  int nthreads = NIMG * A_TOTAL;
  int nblk = (nthreads + 255) / 256;
  hipMemsetAsync(d_ws, 0, WS_ZERO_END, stream);
  k_score<<<nblk, 256, 0, stream>>>(logits, hist, mG, rtG);
  k_cuts<<<1, 1024, 0, stream>>>(hist, cuts);
  k_emit<<<nblk, 256, 0, stream>>>(logits, mG, rtG, cuts, mainL, mcount, bndL, bcount);
  k_refine<<<28, 1024, 0, stream>>>(hist, bndL, bcount, mainL, mcount);
  k_gsel<<<NIMG, 1024, 0, stream>>>(hist, mainL, mcount, priors, reg, boxes, cls, score);
  k_mask<<<NIMG * 500, 256, 0, stream>>>(boxes, cls, mask);
  k_scanfinal<<<NIMG, 256, 0, stream>>>(mask, boxes, cls, score, (float*)d_out);
}

// Round 4
// 281.615 us; speedup vs baseline: 2.4633x; 2.4633x over previous
//
#include <hip/hip_runtime.h>
#include <hip/hip_bf16.h>
#include <math.h>

typedef unsigned long long u64;
typedef unsigned int u32;

#define A_TOTAL 24564
#define NCLS 80
#define NIMG 4
#define NPRE 2000
#define NLV 7
#define HBUCKETS 1024
#define BEXP_BASE 0x3CA3
#define TOTAL_G (NIMG * A_TOTAL)   // 98256
#define BLK_ANCH 128
#define NBLK_SC ((TOTAL_G + BLK_ANCH - 1) / BLK_ANCH)  // 768

__device__ __constant__ int c_klv[NLV] = {1000,1000,1000,1000,1000,1000,320};

// ---- workspace layout (bytes) ----
#define WS_HIST      0          // 28*1024*4 = 114688
#define WS_MCOUNT    114688     // 28*4
#define WS_BCOUNT    114800     // 28*4
#define WS_ZERO_END  114912
#define WS_CUTS      114912     // 28*8 (written every call by k_cuts)
#define WS_MAIN      115136     // 28*1024*8
#define WS_BND       344512     // 28*4096*8
#define WS_BOXES     1326016    // 4*2000*16
#define WS_CLS       1454016    // 4*2000*4
#define WS_SCORE     1486016    // 4*2000*4
#define WS_MASK      1518016    // 4*2000*32*8 = 2048000 (dead until k_mask)
#define WS_M         1518016    // 98256*4 (overlaps mask; dead after k_emit)
#define WS_RT        1911232    // 98256*4

__device__ inline u64 shfl_u64(u64 v, int src) {
  int lo = __shfl((int)(u32)(v & 0xFFFFFFFFULL), src);
  int hi = __shfl((int)(u32)(v >> 32), src);
  return ((u64)(u32)hi << 32) | (u32)lo;
}

__device__ inline int score_bucket(u32 bits) {
  int b = (int)(bits >> 16) - BEXP_BASE;
  return b < 0 ? 0 : (b > HBUCKETS - 1 ? HBUCKETS - 1 : b);
}

__device__ inline int level_of(int a) {
  return (a < 16384) ? 0 : (a < 22528) ? 1 : (a < 24064) ? 2 :
         (a < 24448) ? 3 : (a < 24544) ? 4 : (a < 24560) ? 5 : 6;
}

// One full wave finds (cut bucket, count-in-bucket) for top-k over a 1024-bin
// histogram h. Deterministic: same h,k -> same result.
__device__ inline void wave_find_cut(const u32* __restrict__ h, int k, int lane,
                                     int& cx, int& cy) {
  u32 s = 0;
#pragma unroll
  for (int i = 0; i < 16; ++i) s += h[lane * 16 + i];
  u32 S = s;  // inclusive suffix-sum across lanes
#pragma unroll
  for (int o = 1; o < 64; o <<= 1) {
    u32 t = (u32)__shfl_down((int)S, o);
    if (lane + o < 64) S += t;
  }
  u32 total = (u32)__shfl((int)S, 0);
  if (total <= (u32)k) { cx = -1; cy = 0; return; }
  u64 bm = __ballot(S >= (u32)k);
  int L0 = 63 - (int)__clzll((long long)bm);
  u32 Sup = (u32)__shfl_down((int)S, 1);
  if (lane == 63) Sup = 0;
  int rcx = 0, rcy = 0;
  if (lane == L0) {
    u32 cum = Sup;
    for (int i = 15; i >= 0; --i) {
      u32 c = h[lane * 16 + i];
      if (cum + c >= (u32)k) { rcx = lane * 16 + i; rcy = k - (int)cum; break; }
      cum += c;
    }
  }
  cx = __shfl(rcx, L0);
  cy = __shfl(rcy, L0);
}

// Pass 1: LDS-staged thread-per-anchor softmax. Coalesced float4 staging of
// 128 anchors x 81 logits; each thread walks its own LDS row (stride 81 ==
// 17 mod 32 banks -> conflict-free). Row overwritten with e=expf(x-m) during
// the sum pass (thread-private). Arithmetic order identical to prior round.
__global__ __launch_bounds__(128) void k_score(const float* __restrict__ logits,
                                               u32* __restrict__ histG,
                                               float* __restrict__ mG,
                                               float* __restrict__ rtG) {
  __shared__ float sx[BLK_ANCH * 81];
  __shared__ u32 sh[HBUCKETS];
  int tid = threadIdx.x, bx = blockIdx.x;
  for (int b = tid; b < HBUCKETS; b += BLK_ANCH) sh[b] = 0;
  size_t base_f = (size_t)bx * BLK_ANCH * 81;
  long long rem4 = ((long long)TOTAL_G * 81 - (long long)base_f) / 4;
  int n4 = (rem4 > BLK_ANCH * 81 / 4) ? BLK_ANCH * 81 / 4 : (int)rem4;
  const float4* src = (const float4*)(logits + base_f);
  float4* dst = (float4*)sx;
  for (int t = tid; t < n4; t += BLK_ANCH) dst[t] = src[t];
  __syncthreads();
  int g = bx * BLK_ANCH + tid;
  int g0 = bx * BLK_ANCH;
  int seg0 = (g0 / A_TOTAL) * NLV + level_of(g0 % A_TOTAL);
  bool valid = g < TOTAL_G;
  int seg = seg0;
  float rt = 0.f;
  int rowoff = tid * 81;
  if (valid) {
    int img = g / A_TOTAL;
    seg = img * NLV + level_of(g - img * A_TOTAL);
    float m = sx[rowoff];
#pragma unroll
    for (int i = 1; i < 81; ++i) m = fmaxf(m, sx[rowoff + i]);
    float tsum = 0.f;
    for (int i = 0; i < 81; ++i) {
      float e = expf(sx[rowoff + i] - m);
      tsum += e;
      if (i < 80) sx[rowoff + i] = e;
    }
    rt = 1.0f / tsum;
    mG[g] = m;
    rtG[g] = rt;
  }
  int uniform = __syncthreads_and((int)(!valid || seg == seg0));
  if (valid) {
    u32* hdst = uniform ? sh : (histG + (size_t)seg * HBUCKETS);
    for (int i = 0; i < 80; ++i) {
      float s = sx[rowoff + i] * rt;
      if (s > 0.02f) atomicAdd(&hdst[score_bucket(__float_as_uint(s))], 1u);
    }
  }
  __syncthreads();
  if (uniform) {
    u32* hseg = histG + (size_t)seg0 * HBUCKETS;
    for (int b = tid; b < HBUCKETS; b += BLK_ANCH) {
      u32 v = sh[b];
      if (v) atomicAdd(&hseg[b], v);
    }
  }
}

__global__ __launch_bounds__(1024) void k_cuts(const u32* __restrict__ histG,
                                               int2* __restrict__ cutsG) {
  int wid = threadIdx.x >> 6, lane = threadIdx.x & 63;
  for (int seg = wid; seg < NIMG * NLV; seg += 16) {
    int cx, cy;
    wave_find_cut(histG + (size_t)seg * HBUCKETS, c_klv[seg % NLV], lane, cx, cy);
    if (lane == 0) cutsG[seg] = make_int2(cx, cy);
  }
}

// Pass 2: same staging; recompute s = expf(x-m)*rt from (m,rt) -> identical
// bits to pass 1. Emit above-cut -> mainG, boundary-bucket -> bndG.
__global__ __launch_bounds__(128) void k_emit(const float* __restrict__ logits,
                                              const float* __restrict__ mG,
                                              const float* __restrict__ rtG,
                                              const int2* __restrict__ cutsG,
                                              u64* __restrict__ mainG, u32* __restrict__ mcount,
                                              u64* __restrict__ bndG, u32* __restrict__ bcount) {
  __shared__ float sx[BLK_ANCH * 81];
  int tid = threadIdx.x, bx = blockIdx.x;
  size_t base_f = (size_t)bx * BLK_ANCH * 81;
  long long rem4 = ((long long)TOTAL_G * 81 - (long long)base_f) / 4;
  int n4 = (rem4 > BLK_ANCH * 81 / 4) ? BLK_ANCH * 81 / 4 : (int)rem4;
  const float4* src = (const float4*)(logits + base_f);
  float4* dst = (float4*)sx;
  for (int t = tid; t < n4; t += BLK_ANCH) dst[t] = src[t];
  __syncthreads();
  int g = bx * BLK_ANCH + tid;
  if (g >= TOTAL_G) return;
  int img = g / A_TOTAL;
  int a = g - img * A_TOTAL;
  int seg = img * NLV + level_of(a);
  int2 ct = cutsG[seg];
  float m = mG[g], rt = rtG[g];
  int rowoff = tid * 81;
  for (int i = 0; i < 80; ++i) {
    float s = expf(sx[rowoff + i] - m) * rt;
    if (s > 0.02f) {
      u32 bits = __float_as_uint(s);
      int bk = score_bucket(bits);
      if (bk >= ct.x) {
        u64 key = ((u64)bits << 32) | (u64)(0xFFFFFFFFu - (u32)(a * NCLS + i));
        if (ct.x < 0 || bk > ct.x) {
          u32 p = atomicAdd(&mcount[seg], 1u);
          if (p < 1024) mainG[(size_t)seg * 1024 + p] = key;
        } else {
          u32 p = atomicAdd(&bcount[seg], 1u);
          if (p < 4096) bndG[(size_t)seg * 4096 + p] = key;
        }
      }
    }
  }
}

__device__ inline void bitonic_desc(u64* s, int n) {
  for (int k = 2; k <= n; k <<= 1)
    for (int j = k >> 1; j > 0; j >>= 1) {
      __syncthreads();
      for (int i = threadIdx.x; i < n; i += blockDim.x) {
        int l = i ^ j;
        if (l > i) {
          u64 a = s[i], b = s[l];
          if (((i & k) == 0) ? (a < b) : (a > b)) { s[i] = b; s[l] = a; }
        }
      }
    }
  __syncthreads();
}

// exact per-level top-k: sort only pow2ceil(boundary count) elements
__global__ __launch_bounds__(1024) void k_refine(const u32* __restrict__ histG,
                                                 const u64* __restrict__ bndG,
                                                 const u32* __restrict__ bcount,
                                                 u64* __restrict__ mainG, u32* __restrict__ mcount) {
  int seg = blockIdx.x;
  __shared__ int sh_cx, sh_cy;
  __shared__ u64 s[4096];
  int tid = threadIdx.x, lane = tid & 63;
  if (tid < 64) {
    int cx, cy;
    wave_find_cut(histG + (size_t)seg * HBUCKETS, c_klv[seg % NLV], lane, cx, cy);
    if (lane == 0) { sh_cx = cx; sh_cy = cy; }
  }
  __syncthreads();
  if (sh_cx < 0) return;
  int m = (int)bcount[seg]; if (m > 4096) m = 4096;
  int n = 64; while (n < m) n <<= 1;
  for (int t = tid; t < n; t += 1024)
    s[t] = (t < m) ? bndG[(size_t)seg * 4096 + t] : 0ULL;
  bitonic_desc(s, n);
  int kp = sh_cy; if (kp > m) kp = m;
  int base = (int)mcount[seg];
  for (int t = tid; t < kp; t += 1024) {
    int p = base + t;
    if (p < 1024) mainG[(size_t)seg * 1024 + p] = s[t];
  }
  __syncthreads();
  if (tid == 0) {
    int nb = base + kp;
    mcount[seg] = (u32)(nb > 1024 ? 1024 : nb);
  }
}

// per-image: global cut from truncated per-level histograms, compact <2000
// above-cut, sort tiny boundary, one 2048 bitonic, decode inline.
__global__ __launch_bounds__(1024) void k_gsel(const u32* __restrict__ histG,
                                               const u64* __restrict__ mainG,
                                               const u32* __restrict__ mcount,
                                               const float4* __restrict__ priors,
                                               const float4* __restrict__ reg,
                                               float4* __restrict__ boxesG,
                                               int* __restrict__ clsG,
                                               float* __restrict__ scoreG) {
  int img = blockIdx.x;
  int tid = threadIdx.x, wid = tid >> 6, lane = tid & 63;
  __shared__ u32 H[HBUCKETS];
  __shared__ int lcx[NLV], lcy[NLV];
  __shared__ int sh_gx, sh_gy, sh_m, sh_b;
  __shared__ u64 bnd2[4096];
  __shared__ u64 sel[2048];
  if (tid == 0) { sh_m = 0; sh_b = 0; }
  if (wid < NLV) {
    int cx, cy;
    wave_find_cut(histG + (size_t)(img * NLV + wid) * HBUCKETS, c_klv[wid], lane, cx, cy);
    if (lane == 0) { lcx[wid] = cx; lcy[wid] = cy; }
  }
  __syncthreads();
  for (int b = tid; b < HBUCKETS; b += 1024) {
    u32 acc = 0;
#pragma unroll
    for (int l = 0; l < NLV; ++l) {
      u32 h = histG[(size_t)(img * NLV + l) * HBUCKETS + b];
      int cx = lcx[l];
      if (cx < 0 || b > cx) acc += h;
      else if (b == cx) acc += (u32)lcy[l];
    }
    H[b] = acc;
  }
  __syncthreads();
  if (wid == 0) {
    int gx, gy;
    wave_find_cut(H, NPRE, lane, gx, gy);
    if (lane == 0) { sh_gx = gx; sh_gy = gy; }
  }
  __syncthreads();
  int gx = sh_gx, gy = sh_gy;
  for (int l = 0; l < NLV; ++l) {
    int cnt = (int)mcount[img * NLV + l]; if (cnt > 1024) cnt = 1024;
    for (int t = tid; t < cnt; t += 1024) {
      u64 key = mainG[(size_t)(img * NLV + l) * 1024 + t];
      int b = (int)(key >> 48) - BEXP_BASE;
      b = b < 0 ? 0 : (b > HBUCKETS - 1 ? HBUCKETS - 1 : b);
      if (gx < 0 || b > gx) { int p = atomicAdd(&sh_m, 1); if (p < 2048) sel[p] = key; }
      else if (b == gx)     { int p = atomicAdd(&sh_b, 1); if (p < 4096) bnd2[p] = key; }
    }
  }
  __syncthreads();
  int msel = sh_m; if (msel > 2048) msel = 2048;
  int nb = sh_b; if (nb > 4096) nb = 4096;
  int take = 0;
  if (gx >= 0) {
    int n = 64; while (n < nb) n <<= 1;
    for (int t = tid; t < n; t += 1024) if (t >= nb) bnd2[t] = 0ULL;
    bitonic_desc(bnd2, n);
    take = gy; if (take > nb) take = nb;
    if (msel + take > 2048) take = 2048 - msel;
    for (int t = tid; t < take; t += 1024) sel[msel + t] = bnd2[t];
  }
  int tot = msel + take;
  for (int t = tid; t < 2048; t += 1024) if (t >= tot) sel[t] = 0ULL;
  bitonic_desc(sel, 2048);
  for (int t = tid; t < NPRE; t += 1024) {
    u64 key = sel[t];
    float4 bx = make_float4(0.f, 0.f, 0.f, 0.f);
    int c = -1;
    float sc = 0.f;
    if (key != 0ULL) {
      sc = __uint_as_float((u32)(key >> 32));
      u32 flat = 0xFFFFFFFFu - (u32)(key & 0xFFFFFFFFULL);
      int a = (int)(flat / NCLS);
      c = (int)(flat % NCLS);
      float4 p = priors[a];
      float4 r = reg[(size_t)img * A_TOTAL + a];
      float cx = p.x + (r.x * 0.1f) * p.z;
      float cy = p.y + (r.y * 0.1f) * p.w;
      float w = p.z * expf(r.z * 0.2f);
      float h = p.w * expf(r.w * 0.2f);
      bx.x = fminf(fmaxf(cx - w * 0.5f, 0.f), 512.f);
      bx.y = fminf(fmaxf(cy - h * 0.5f, 0.f), 512.f);
      bx.z = fminf(fmaxf(cx + w * 0.5f, 0.f), 512.f);
      bx.w = fminf(fmaxf(cy + h * 0.5f, 0.f), 512.f);
    }
    boxesG[(size_t)img * NPRE + t] = bx;
    clsG[(size_t)img * NPRE + t] = c;
    scoreG[(size_t)img * NPRE + t] = sc;
  }
}

// suppression bitmask: row i, bit j set iff j>i, same class, IoU>0.45
__global__ __launch_bounds__(256) void k_mask(const float4* __restrict__ boxesG,
                                              const int* __restrict__ clsG,
                                              u64* __restrict__ maskG) {
  __shared__ float4 lb[NPRE];
  __shared__ int lc[NPRE];
  int img = blockIdx.x / 500;
  int rb = (blockIdx.x % 500) * 4;
  for (int t = threadIdx.x; t < NPRE; t += 256) {
    lb[t] = boxesG[(size_t)img * NPRE + t];
    lc[t] = clsG[(size_t)img * NPRE + t];
  }
  __syncthreads();
  int w = threadIdx.x >> 6, lane = threadIdx.x & 63;
  int i = rb + w;
  float4 bi = lb[i];
  int ci = lc[i];
  float ai = (bi.z - bi.x) * (bi.w - bi.y);
  u64* mrow = maskG + ((size_t)img * NPRE + i) * 32;
  for (int ch = 0; ch < 32; ++ch) {
    int j = ch * 64 + lane;
    bool pred = false;
    if (j < NPRE && j > i) {
      if (lc[j] == ci) {
        float4 bj = lb[j];
        float xx1 = fmaxf(bi.x, bj.x), yy1 = fmaxf(bi.y, bj.y);
        float xx2 = fminf(bi.z, bj.z), yy2 = fminf(bi.w, bj.w);
        float ww = fmaxf(xx2 - xx1, 0.f), hh = fmaxf(yy2 - yy1, 0.f);
        float inter = ww * hh;
        float aj = (bj.z - bj.x) * (bj.w - bj.y);
        float iou = inter / fmaxf(ai + aj - inter, 1e-6f);
        pred = iou > 0.45f;
      }
    }
    u64 word = __ballot(pred);
    if (lane == 0) mrow[ch] = word;
  }
}

// greedy scan with early exit at 200 kept, fused with final gather.
__global__ __launch_bounds__(256) void k_scanfinal(const u64* __restrict__ maskG,
                                                   const float4* __restrict__ boxesG,
                                                   const int* __restrict__ clsG,
                                                   const float* __restrict__ scoreG,
                                                   float* __restrict__ out) {
  int img = blockIdx.x;
  int tid = threadIdx.x;
  __shared__ u64 sh_remv[32];
  __shared__ u32 keptList[216];
  __shared__ int sh_cnt, sh_done;
  __shared__ int kpref[257];
  __shared__ unsigned short S[NPRE];
  if (tid == 0) { sh_cnt = 0; sh_done = 0; }
  __syncthreads();
  if (tid < 64) {
    int lane = tid;
    int wl = lane & 31;
    const u64* M = maskG + (size_t)img * NPRE * 32;
    u64 remv = 0;
    u64 cur[16], nxt[16];
    int cnt = 0;
#pragma unroll
    for (int r = 0; r < 16; ++r) cur[r] = M[(size_t)r * 32 + wl];
    int t = 0;
    for (; t < 125; ++t) {
      if (t < 124) {
#pragma unroll
        for (int r = 0; r < 16; ++r) nxt[r] = M[(size_t)((t + 1) * 16 + r) * 32 + wl];
      }
#pragma unroll
      for (int r = 0; r < 16; ++r) {
        int i = t * 16 + r;
        u64 rm = shfl_u64(remv, i >> 6);
        if (!((rm >> (i & 63)) & 1ULL)) {
          remv |= cur[r];
          if (lane == 0 && cnt < 216) keptList[cnt] = (u32)i;
          ++cnt;
        }
      }
#pragma unroll
      for (int r = 0; r < 16; ++r) cur[r] = nxt[r];
      if (cnt >= 200) { ++t; break; }
    }
    if (lane == 0) sh_cnt = cnt < 216 ? cnt : 216;
    if (t >= 125) {
      if (lane == 0) sh_done = 1;
      if (lane < 32) sh_remv[lane] = remv;
    }
  }
  __syncthreads();
  int nK = sh_cnt;
  if (sh_done && nK < 200) {
    int base = tid * 8;
    bool sb[8];
    int scnt = 0;
#pragma unroll
    for (int e = 0; e < 8; ++e) {
      int i = base + e;
      bool sup = (i < NPRE) && ((sh_remv[i >> 6] >> (i & 63)) & 1ULL);
      sb[e] = sup;
      scnt += sup ? 1 : 0;
    }
    kpref[tid + 1] = scnt;
    if (tid == 0) kpref[0] = 0;
    __syncthreads();
    if (tid == 0) {
      int acc = 0;
      for (int t = 1; t <= 256; ++t) { acc += kpref[t]; kpref[t] = acc; }
    }
    __syncthreads();
    int sp = kpref[tid];
#pragma unroll
    for (int e = 0; e < 8; ++e) {
      int i = base + e;
      if (i < NPRE && sb[e]) S[sp++] = (unsigned short)i;
    }
    __syncthreads();
    if (tid < 200) {
      float fv = 0.f;
      float4 fb = make_float4(0.f, 0.f, 0.f, 0.f);
      int fc;
      if (tid < nK) {
        int idx = (int)keptList[tid];
        fv = scoreG[(size_t)img * NPRE + idx];
        fb = boxesG[(size_t)img * NPRE + idx];
        fc = clsG[(size_t)img * NPRE + idx];
      } else {
        int idx = S[tid - nK];
        fc = clsG[(size_t)img * NPRE + idx];
      }
      float* fbo = out + (size_t)img * 800 + tid * 4;
      fbo[0] = fb.x; fbo[1] = fb.y; fbo[2] = fb.z; fbo[3] = fb.w;
      out[3200 + (size_t)img * 200 + tid] = fv;
      out[4000 + (size_t)img * 200 + tid] = (float)fc;
    }
  } else {
    if (tid < 200) {
      int idx = (int)keptList[tid];
      float fv = scoreG[(size_t)img * NPRE + idx];
      float4 fb = boxesG[(size_t)img * NPRE + idx];
      int fc = clsG[(size_t)img * NPRE + idx];
      float* fbo = out + (size_t)img * 800 + tid * 4;
      fbo[0] = fb.x; fbo[1] = fb.y; fbo[2] = fb.z; fbo[3] = fb.w;
      out[3200 + (size_t)img * 200 + tid] = fv;
      out[4000 + (size_t)img * 200 + tid] = (float)fc;
    }
  }
}

extern "C" void kernel_launch(void* const* d_in, const int* in_sizes, int n_in,
                              void* d_out, int out_size, void* d_ws, size_t ws_size,
                              hipStream_t stream) {
  const float* logits = (const float*)d_in[0];
  const float4* reg = (const float4*)d_in[1];
  const float4* priors = (const float4*)d_in[2];
  char* ws = (char*)d_ws;
  u32* hist = (u32*)(ws + WS_HIST);
  u32* mcount = (u32*)(ws + WS_MCOUNT);
  u32* bcount = (u32*)(ws + WS_BCOUNT);
  int2* cuts = (int2*)(ws + WS_CUTS);
  u64* mainL = (u64*)(ws + WS_MAIN);
  u64* bndL = (u64*)(ws + WS_BND);
  float4* boxes = (float4*)(ws + WS_BOXES);
  int* cls = (int*)(ws + WS_CLS);
  float* score = (float*)(ws + WS_SCORE);
  u64* mask = (u64*)(ws + WS_MASK);
  float* mG = (float*)(ws + WS_M);
  float* rtG = (float*)(ws + WS_RT);

  hipMemsetAsync(d_ws, 0, WS_ZERO_END, stream);
  k_score<<<NBLK_SC, BLK_ANCH, 0, stream>>>(logits, hist, mG, rtG);
  k_cuts<<<1, 1024, 0, stream>>>(hist, cuts);
  k_emit<<<NBLK_SC, BLK_ANCH, 0, stream>>>(logits, mG, rtG, cuts, mainL, mcount, bndL, bcount);
  k_refine<<<28, 1024, 0, stream>>>(hist, bndL, bcount, mainL, mcount);
  k_gsel<<<NIMG, 1024, 0, stream>>>(hist, mainL, mcount, priors, reg, boxes, cls, score);
  k_mask<<<NIMG * 500, 256, 0, stream>>>(boxes, cls, mask);
  k_scanfinal<<<NIMG, 256, 0, stream>>>(mask, boxes, cls, score, (float*)d_out);
}

// Round 5
// 169.993 us; speedup vs baseline: 4.0807x; 1.6566x over previous
//
#include <hip/hip_runtime.h>
#include <hip/hip_bf16.h>
#include <math.h>

typedef unsigned long long u64;
typedef unsigned int u32;

#define A_TOTAL 24564
#define NCLS 80
#define NIMG 4
#define NPRE 2000
#define NLV 7
#define HBUCKETS 1024
#define BEXP_BASE 0x3CA3
#define TOTAL_G (NIMG * A_TOTAL)   // 98256
#define SC_A 128                   // anchors per block
#define SC_T 512                   // threads per block (4 per anchor)
#define NBLK_SC ((TOTAL_G + SC_A - 1) / SC_A)  // 768
#define MCAP 256
#define BCAP 128

__device__ __constant__ int c_klv[NLV] = {1000,1000,1000,1000,1000,1000,320};

// ---- workspace layout (bytes) ----
#define WS_HIST      0          // 28*1024*4 = 114688
#define WS_MCOUNT    114688     // 28*4
#define WS_BCOUNT    114800     // 28*4
#define WS_ZERO_END  114912
#define WS_MAIN      115136     // 28*1024*8
#define WS_BND       344512     // 28*4096*8
#define WS_BOXES     1326016    // 4*2000*16
#define WS_CLS       1454016    // 4*2000*4
#define WS_SCORE     1486016    // 4*2000*4
#define WS_MASK      1518016    // 4*2000*32*8 = 2048000 (dead until k_mask)
#define WS_MRT       1518016    // 98256*8 float2 (overlaps mask; dead after k_emit)

__device__ inline u64 shfl_u64(u64 v, int src) {
  int lo = __shfl((int)(u32)(v & 0xFFFFFFFFULL), src);
  int hi = __shfl((int)(u32)(v >> 32), src);
  return ((u64)(u32)hi << 32) | (u32)lo;
}

__device__ inline int score_bucket(u32 bits) {
  int b = (int)(bits >> 16) - BEXP_BASE;
  return b < 0 ? 0 : (b > HBUCKETS - 1 ? HBUCKETS - 1 : b);
}

__device__ inline int level_of(int a) {
  return (a < 16384) ? 0 : (a < 22528) ? 1 : (a < 24064) ? 2 :
         (a < 24448) ? 3 : (a < 24544) ? 4 : (a < 24560) ? 5 : 6;
}

// One full wave finds (cut bucket, count-in-bucket) for top-k over a 1024-bin
// histogram h. Deterministic: same h,k -> same result.
__device__ inline void wave_find_cut(const u32* __restrict__ h, int k, int lane,
                                     int& cx, int& cy) {
  u32 s = 0;
#pragma unroll
  for (int i = 0; i < 16; ++i) s += h[lane * 16 + i];
  u32 S = s;  // inclusive suffix-sum across lanes
#pragma unroll
  for (int o = 1; o < 64; o <<= 1) {
    u32 t = (u32)__shfl_down((int)S, o);
    if (lane + o < 64) S += t;
  }
  u32 total = (u32)__shfl((int)S, 0);
  if (total <= (u32)k) { cx = -1; cy = 0; return; }
  u64 bm = __ballot(S >= (u32)k);
  int L0 = 63 - (int)__clzll((long long)bm);
  u32 Sup = (u32)__shfl_down((int)S, 1);
  if (lane == 63) Sup = 0;
  int rcx = 0, rcy = 0;
  if (lane == L0) {
    u32 cum = Sup;
    for (int i = 15; i >= 0; --i) {
      u32 c = h[lane * 16 + i];
      if (cum + c >= (u32)k) { rcx = lane * 16 + i; rcy = k - (int)cum; break; }
      cum += c;
    }
  }
  cx = __shfl(rcx, L0);
  cy = __shfl(rcy, L0);
}

// Pass 1: LDS-staged, 4 threads per anchor (20 classes each; q==3 also owns
// class 80 for max/sum). Quad-reduce m and t via in-quad shfl_xor (1,2) --
// deterministic fixed combine order. e-values stay in registers. Per-element
// score s = e[i]*rt is order-free, so pass 2 reproduces identical bits from
// stored (m, rt).
__global__ __launch_bounds__(SC_T) void k_score(const float* __restrict__ logits,
                                                u32* __restrict__ histG,
                                                float2* __restrict__ mrtG) {
  __shared__ float sx[SC_A * 81];   // 41472 B
  __shared__ u32 sh[HBUCKETS];      // 4096 B
  int tid = threadIdx.x, bx = blockIdx.x;
  for (int b = tid; b < HBUCKETS; b += SC_T) sh[b] = 0;
  size_t base_f = (size_t)bx * SC_A * 81;
  long long rem4 = ((long long)TOTAL_G * 81 - (long long)base_f) / 4;
  int cap4 = SC_A * 81 / 4;
  int n4 = (rem4 > cap4) ? cap4 : (int)rem4;
  const float4* src = (const float4*)(logits + base_f);
  float4* dst = (float4*)sx;
  for (int t = tid; t < n4; t += SC_T) dst[t] = src[t];
  __syncthreads();
  int la = tid >> 2, q = tid & 3;
  int g = bx * SC_A + la;
  bool valid = g < TOTAL_G;
  int g0 = bx * SC_A;
  int seg0 = (g0 / A_TOTAL) * NLV + level_of(g0 % A_TOTAL);
  int seg = seg0;
  int rowoff = la * 81, c0 = q * 20;
  float e[21];
  float rt = 0.f;
  if (valid) {
    int img = g / A_TOTAL;
    seg = img * NLV + level_of(g - img * A_TOTAL);
    float mloc = sx[rowoff + c0];
#pragma unroll
    for (int i = 1; i < 20; ++i) mloc = fmaxf(mloc, sx[rowoff + c0 + i]);
    if (q == 3) mloc = fmaxf(mloc, sx[rowoff + 80]);
    float m = fmaxf(mloc, __shfl_xor(mloc, 1));
    m = fmaxf(m, __shfl_xor(m, 2));
    float tq = 0.f;
#pragma unroll
    for (int i = 0; i < 20; ++i) { e[i] = expf(sx[rowoff + c0 + i] - m); tq += e[i]; }
    if (q == 3) tq += expf(sx[rowoff + 80] - m);
    float t = tq + __shfl_xor(tq, 1);
    t = t + __shfl_xor(t, 2);
    rt = 1.0f / t;
    if (q == 0) mrtG[g] = make_float2(m, rt);
  }
  int uniform = __syncthreads_and((int)(!valid || seg == seg0));
  if (valid) {
    u32* hdst = uniform ? sh : (histG + (size_t)seg * HBUCKETS);
#pragma unroll
    for (int i = 0; i < 20; ++i) {
      float s = e[i] * rt;
      if (s > 0.02f) atomicAdd(&hdst[score_bucket(__float_as_uint(s))], 1u);
    }
  }
  __syncthreads();
  if (uniform) {
    u32* hseg = histG + (size_t)seg0 * HBUCKETS;
    for (int b = tid; b < HBUCKETS; b += SC_T) {
      u32 v = sh[b];
      if (v) atomicAdd(&hseg[b], v);
    }
  }
}

// Pass 2: same staging/mapping; cuts computed per-block (<=4 segs); winners
// collected in LDS lists (overflow -> direct global path, still correct),
// then ONE global atomicAdd per (block,seg) reserves slots; coalesced-ish
// scatter copy. Downstream treats mainG as a set and sorts bndG by full
// 64-bit key, so intra-seg order is irrelevant.
__global__ __launch_bounds__(SC_T) void k_emit(const float* __restrict__ logits,
                                               const float2* __restrict__ mrtG,
                                               const u32* __restrict__ histG,
                                               u64* __restrict__ mainG, u32* __restrict__ mcount,
                                               u64* __restrict__ bndG, u32* __restrict__ bcount) {
  __shared__ float sx[SC_A * 81];
  __shared__ int lcx4[4];
  __shared__ u64 mk[MCAP]; __shared__ unsigned char msg_[MCAP];
  __shared__ u64 bkl[BCAP]; __shared__ unsigned char bsg[BCAP];
  __shared__ int nm, nb, cm[4], cb[4], basem[4], baseb[4], wm[4], wb[4];
  int tid = threadIdx.x, bx = blockIdx.x;
  if (tid < 4) { cm[tid] = 0; cb[tid] = 0; wm[tid] = 0; wb[tid] = 0; }
  if (tid == 0) { nm = 0; nb = 0; }
  size_t base_f = (size_t)bx * SC_A * 81;
  long long rem4 = ((long long)TOTAL_G * 81 - (long long)base_f) / 4;
  int cap4 = SC_A * 81 / 4;
  int n4 = (rem4 > cap4) ? cap4 : (int)rem4;
  const float4* src = (const float4*)(logits + base_f);
  float4* dst = (float4*)sx;
  for (int t = tid; t < n4; t += SC_T) dst[t] = src[t];
  int g0 = bx * SC_A;
  int gN = (g0 + SC_A - 1 < TOTAL_G - 1) ? g0 + SC_A - 1 : TOTAL_G - 1;
  int seg_lo = (g0 / A_TOTAL) * NLV + level_of(g0 % A_TOTAL);
  int seg_hi = (gN / A_TOTAL) * NLV + level_of(gN % A_TOTAL);
  int nseg = seg_hi - seg_lo + 1;   // <= 4 by construction
  int wid = tid >> 6, lane = tid & 63;
  if (wid < nseg) {
    int cx, cy;
    wave_find_cut(histG + (size_t)(seg_lo + wid) * HBUCKETS,
                  c_klv[(seg_lo + wid) % NLV], lane, cx, cy);
    if (lane == 0) lcx4[wid] = cx;
  }
  __syncthreads();
  int la = tid >> 2, q = tid & 3;
  int g = bx * SC_A + la;
  if (g < TOTAL_G) {
    int img = g / A_TOTAL;
    int a = g - img * A_TOTAL;
    int seg = img * NLV + level_of(a);
    int si = seg - seg_lo;
    int ctx = lcx4[si];
    float2 mrt = mrtG[g];
    int rowoff = la * 81, c0 = q * 20;
    for (int i = 0; i < 20; ++i) {
      float s = expf(sx[rowoff + c0 + i] - mrt.x) * mrt.y;
      if (s > 0.02f) {
        u32 bits = __float_as_uint(s);
        int bkt = score_bucket(bits);
        if (bkt >= ctx) {
          u64 key = ((u64)bits << 32) | (u64)(0xFFFFFFFFu - (u32)(a * NCLS + c0 + i));
          if (ctx < 0 || bkt > ctx) {
            int p = atomicAdd(&nm, 1);
            if (p < MCAP) { mk[p] = key; msg_[p] = (unsigned char)si; atomicAdd(&cm[si], 1); }
            else { u32 pg = atomicAdd(&mcount[seg], 1u); if (pg < 1024) mainG[(size_t)seg * 1024 + pg] = key; }
          } else {
            int p = atomicAdd(&nb, 1);
            if (p < BCAP) { bkl[p] = key; bsg[p] = (unsigned char)si; atomicAdd(&cb[si], 1); }
            else { u32 pg = atomicAdd(&bcount[seg], 1u); if (pg < 4096) bndG[(size_t)seg * 4096 + pg] = key; }
          }
        }
      }
    }
  }
  __syncthreads();
  if (tid < nseg) {
    if (cm[tid] > 0) basem[tid] = (int)atomicAdd(&mcount[seg_lo + tid], (u32)cm[tid]);
    if (cb[tid] > 0) baseb[tid] = (int)atomicAdd(&bcount[seg_lo + tid], (u32)cb[tid]);
  }
  __syncthreads();
  int tm = nm < MCAP ? nm : MCAP;
  for (int idx = tid; idx < tm; idx += SC_T) {
    int si = msg_[idx];
    int slot = atomicAdd(&wm[si], 1);
    int dstp = basem[si] + slot;
    if (dstp < 1024) mainG[(size_t)(seg_lo + si) * 1024 + dstp] = mk[idx];
  }
  int tb = nb < BCAP ? nb : BCAP;
  for (int idx = tid; idx < tb; idx += SC_T) {
    int si = bsg[idx];
    int slot = atomicAdd(&wb[si], 1);
    int dstp = baseb[si] + slot;
    if (dstp < 4096) bndG[(size_t)(seg_lo + si) * 4096 + dstp] = bkl[idx];
  }
}

__device__ inline void bitonic_desc(u64* s, int n) {
  for (int k = 2; k <= n; k <<= 1)
    for (int j = k >> 1; j > 0; j >>= 1) {
      __syncthreads();
      for (int i = threadIdx.x; i < n; i += blockDim.x) {
        int l = i ^ j;
        if (l > i) {
          u64 a = s[i], b = s[l];
          if (((i & k) == 0) ? (a < b) : (a > b)) { s[i] = b; s[l] = a; }
        }
      }
    }
  __syncthreads();
}

// exact per-level top-k: sort only pow2ceil(boundary count) elements
__global__ __launch_bounds__(1024) void k_refine(const u32* __restrict__ histG,
                                                 const u64* __restrict__ bndG,
                                                 const u32* __restrict__ bcount,
                                                 u64* __restrict__ mainG, u32* __restrict__ mcount) {
  int seg = blockIdx.x;
  __shared__ int sh_cx, sh_cy;
  __shared__ u64 s[4096];
  int tid = threadIdx.x, lane = tid & 63;
  if (tid < 64) {
    int cx, cy;
    wave_find_cut(histG + (size_t)seg * HBUCKETS, c_klv[seg % NLV], lane, cx, cy);
    if (lane == 0) { sh_cx = cx; sh_cy = cy; }
  }
  __syncthreads();
  if (sh_cx < 0) return;
  int m = (int)bcount[seg]; if (m > 4096) m = 4096;
  int n = 64; while (n < m) n <<= 1;
  for (int t = tid; t < n; t += 1024)
    s[t] = (t < m) ? bndG[(size_t)seg * 4096 + t] : 0ULL;
  bitonic_desc(s, n);
  int kp = sh_cy; if (kp > m) kp = m;
  int base = (int)mcount[seg];
  for (int t = tid; t < kp; t += 1024) {
    int p = base + t;
    if (p < 1024) mainG[(size_t)seg * 1024 + p] = s[t];
  }
  __syncthreads();
  if (tid == 0) {
    int nb = base + kp;
    mcount[seg] = (u32)(nb > 1024 ? 1024 : nb);
  }
}

// per-image: global cut from truncated per-level histograms, compact <2000
// above-cut, sort tiny boundary, one 2048 bitonic, decode inline.
__global__ __launch_bounds__(1024) void k_gsel(const u32* __restrict__ histG,
                                               const u64* __restrict__ mainG,
                                               const u32* __restrict__ mcount,
                                               const float4* __restrict__ priors,
                                               const float4* __restrict__ reg,
                                               float4* __restrict__ boxesG,
                                               int* __restrict__ clsG,
                                               float* __restrict__ scoreG) {
  int img = blockIdx.x;
  int tid = threadIdx.x, wid = tid >> 6, lane = tid & 63;
  __shared__ u32 H[HBUCKETS];
  __shared__ int lcx[NLV], lcy[NLV];
  __shared__ int sh_gx, sh_gy, sh_m, sh_b;
  __shared__ u64 bnd2[4096];
  __shared__ u64 sel[2048];
  if (tid == 0) { sh_m = 0; sh_b = 0; }
  if (wid < NLV) {
    int cx, cy;
    wave_find_cut(histG + (size_t)(img * NLV + wid) * HBUCKETS, c_klv[wid], lane, cx, cy);
    if (lane == 0) { lcx[wid] = cx; lcy[wid] = cy; }
  }
  __syncthreads();
  for (int b = tid; b < HBUCKETS; b += 1024) {
    u32 acc = 0;
#pragma unroll
    for (int l = 0; l < NLV; ++l) {
      u32 h = histG[(size_t)(img * NLV + l) * HBUCKETS + b];
      int cx = lcx[l];
      if (cx < 0 || b > cx) acc += h;
      else if (b == cx) acc += (u32)lcy[l];
    }
    H[b] = acc;
  }
  __syncthreads();
  if (wid == 0) {
    int gx, gy;
    wave_find_cut(H, NPRE, lane, gx, gy);
    if (lane == 0) { sh_gx = gx; sh_gy = gy; }
  }
  __syncthreads();
  int gx = sh_gx, gy = sh_gy;
  for (int l = 0; l < NLV; ++l) {
    int cnt = (int)mcount[img * NLV + l]; if (cnt > 1024) cnt = 1024;
    for (int t = tid; t < cnt; t += 1024) {
      u64 key = mainG[(size_t)(img * NLV + l) * 1024 + t];
      int b = (int)(key >> 48) - BEXP_BASE;
      b = b < 0 ? 0 : (b > HBUCKETS - 1 ? HBUCKETS - 1 : b);
      if (gx < 0 || b > gx) { int p = atomicAdd(&sh_m, 1); if (p < 2048) sel[p] = key; }
      else if (b == gx)     { int p = atomicAdd(&sh_b, 1); if (p < 4096) bnd2[p] = key; }
    }
  }
  __syncthreads();
  int msel = sh_m; if (msel > 2048) msel = 2048;
  int nb = sh_b; if (nb > 4096) nb = 4096;
  int take = 0;
  if (gx >= 0) {
    int n = 64; while (n < nb) n <<= 1;
    for (int t = tid; t < n; t += 1024) if (t >= nb) bnd2[t] = 0ULL;
    bitonic_desc(bnd2, n);
    take = gy; if (take > nb) take = nb;
    if (msel + take > 2048) take = 2048 - msel;
    for (int t = tid; t < take; t += 1024) sel[msel + t] = bnd2[t];
  }
  int tot = msel + take;
  for (int t = tid; t < 2048; t += 1024) if (t >= tot) sel[t] = 0ULL;
  bitonic_desc(sel, 2048);
  for (int t = tid; t < NPRE; t += 1024) {
    u64 key = sel[t];
    float4 bx = make_float4(0.f, 0.f, 0.f, 0.f);
    int c = -1;
    float sc = 0.f;
    if (key != 0ULL) {
      sc = __uint_as_float((u32)(key >> 32));
      u32 flat = 0xFFFFFFFFu - (u32)(key & 0xFFFFFFFFULL);
      int a = (int)(flat / NCLS);
      c = (int)(flat % NCLS);
      float4 p = priors[a];
      float4 r = reg[(size_t)img * A_TOTAL + a];
      float cx = p.x + (r.x * 0.1f) * p.z;
      float cy = p.y + (r.y * 0.1f) * p.w;
      float w = p.z * expf(r.z * 0.2f);
      float h = p.w * expf(r.w * 0.2f);
      bx.x = fminf(fmaxf(cx - w * 0.5f, 0.f), 512.f);
      bx.y = fminf(fmaxf(cy - h * 0.5f, 0.f), 512.f);
      bx.z = fminf(fmaxf(cx + w * 0.5f, 0.f), 512.f);
      bx.w = fminf(fmaxf(cy + h * 0.5f, 0.f), 512.f);
    }
    boxesG[(size_t)img * NPRE + t] = bx;
    clsG[(size_t)img * NPRE + t] = c;
    scoreG[(size_t)img * NPRE + t] = sc;
  }
}

// suppression bitmask: row i, bit j set iff j>i, same class, IoU>0.45
__global__ __launch_bounds__(256) void k_mask(const float4* __restrict__ boxesG,
                                              const int* __restrict__ clsG,
                                              u64* __restrict__ maskG) {
  __shared__ float4 lb[NPRE];
  __shared__ int lc[NPRE];
  int img = blockIdx.x / 500;
  int rb = (blockIdx.x % 500) * 4;
  for (int t = threadIdx.x; t < NPRE; t += 256) {
    lb[t] = boxesG[(size_t)img * NPRE + t];
    lc[t] = clsG[(size_t)img * NPRE + t];
  }
  __syncthreads();
  int w = threadIdx.x >> 6, lane = threadIdx.x & 63;
  int i = rb + w;
  float4 bi = lb[i];
  int ci = lc[i];
  float ai = (bi.z - bi.x) * (bi.w - bi.y);
  u64* mrow = maskG + ((size_t)img * NPRE + i) * 32;
  for (int ch = 0; ch < 32; ++ch) {
    int j = ch * 64 + lane;
    bool pred = false;
    if (j < NPRE && j > i) {
      if (lc[j] == ci) {
        float4 bj = lb[j];
        float xx1 = fmaxf(bi.x, bj.x), yy1 = fmaxf(bi.y, bj.y);
        float xx2 = fminf(bi.z, bj.z), yy2 = fminf(bi.w, bj.w);
        float ww = fmaxf(xx2 - xx1, 0.f), hh = fmaxf(yy2 - yy1, 0.f);
        float inter = ww * hh;
        float aj = (bj.z - bj.x) * (bj.w - bj.y);
        float iou = inter / fmaxf(ai + aj - inter, 1e-6f);
        pred = iou > 0.45f;
      }
    }
    u64 word = __ballot(pred);
    if (lane == 0) mrow[ch] = word;
  }
}

// greedy scan with early exit at 200 kept, fused with final gather.
__global__ __launch_bounds__(256) void k_scanfinal(const u64* __restrict__ maskG,
                                                   const float4* __restrict__ boxesG,
                                                   const int* __restrict__ clsG,
                                                   const float* __restrict__ scoreG,
                                                   float* __restrict__ out) {
  int img = blockIdx.x;
  int tid = threadIdx.x;
  __shared__ u64 sh_remv[32];
  __shared__ u32 keptList[216];
  __shared__ int sh_cnt, sh_done;
  __shared__ int kpref[257];
  __shared__ unsigned short S[NPRE];
  if (tid == 0) { sh_cnt = 0; sh_done = 0; }
  __syncthreads();
  if (tid < 64) {
    int lane = tid;
    int wl = lane & 31;
    const u64* M = maskG + (size_t)img * NPRE * 32;
    u64 remv = 0;
    u64 cur[16], nxt[16];
    int cnt = 0;
#pragma unroll
    for (int r = 0; r < 16; ++r) cur[r] = M[(size_t)r * 32 + wl];
    int t = 0;
    for (; t < 125; ++t) {
      if (t < 124) {
#pragma unroll
        for (int r = 0; r < 16; ++r) nxt[r] = M[(size_t)((t + 1) * 16 + r) * 32 + wl];
      }
#pragma unroll
      for (int r = 0; r < 16; ++r) {
        int i = t * 16 + r;
        u64 rm = shfl_u64(remv, i >> 6);
        if (!((rm >> (i & 63)) & 1ULL)) {
          remv |= cur[r];
          if (lane == 0 && cnt < 216) keptList[cnt] = (u32)i;
          ++cnt;
        }
      }
#pragma unroll
      for (int r = 0; r < 16; ++r) cur[r] = nxt[r];
      if (cnt >= 200) { ++t; break; }
    }
    if (lane == 0) sh_cnt = cnt < 216 ? cnt : 216;
    if (t >= 125) {
      if (lane == 0) sh_done = 1;
      if (lane < 32) sh_remv[lane] = remv;
    }
  }
  __syncthreads();
  int nK = sh_cnt;
  if (sh_done && nK < 200) {
    int base = tid * 8;
    bool sb[8];
    int scnt = 0;
#pragma unroll
    for (int e = 0; e < 8; ++e) {
      int i = base + e;
      bool sup = (i < NPRE) && ((sh_remv[i >> 6] >> (i & 63)) & 1ULL);
      sb[e] = sup;
      scnt += sup ? 1 : 0;
    }
    kpref[tid + 1] = scnt;
    if (tid == 0) kpref[0] = 0;
    __syncthreads();
    if (tid == 0) {
      int acc = 0;
      for (int t = 1; t <= 256; ++t) { acc += kpref[t]; kpref[t] = acc; }
    }
    __syncthreads();
    int sp = kpref[tid];
#pragma unroll
    for (int e = 0; e < 8; ++e) {
      int i = base + e;
      if (i < NPRE && sb[e]) S[sp++] = (unsigned short)i;
    }
    __syncthreads();
    if (tid < 200) {
      float fv = 0.f;
      float4 fb = make_float4(0.f, 0.f, 0.f, 0.f);
      int fc;
      if (tid < nK) {
        int idx = (int)keptList[tid];
        fv = scoreG[(size_t)img * NPRE + idx];
        fb = boxesG[(size_t)img * NPRE + idx];
        fc = clsG[(size_t)img * NPRE + idx];
      } else {
        int idx = S[tid - nK];
        fc = clsG[(size_t)img * NPRE + idx];
      }
      float* fbo = out + (size_t)img * 800 + tid * 4;
      fbo[0] = fb.x; fbo[1] = fb.y; fbo[2] = fb.z; fbo[3] = fb.w;
      out[3200 + (size_t)img * 200 + tid] = fv;
      out[4000 + (size_t)img * 200 + tid] = (float)fc;
    }
  } else {
    if (tid < 200) {
      int idx = (int)keptList[tid];
      float fv = scoreG[(size_t)img * NPRE + idx];
      float4 fb = boxesG[(size_t)img * NPRE + idx];
      int fc = clsG[(size_t)img * NPRE + idx];
      float* fbo = out + (size_t)img * 800 + tid * 4;
      fbo[0] = fb.x; fbo[1] = fb.y; fbo[2] = fb.z; fbo[3] = fb.w;
      out[3200 + (size_t)img * 200 + tid] = fv;
      out[4000 + (size_t)img * 200 + tid] = (float)fc;
    }
  }
}

extern "C" void kernel_launch(void* const* d_in, const int* in_sizes, int n_in,
                              void* d_out, int out_size, void* d_ws, size_t ws_size,
                              hipStream_t stream) {
  const float* logits = (const float*)d_in[0];
  const float4* reg = (const float4*)d_in[1];
  const float4* priors = (const float4*)d_in[2];
  char* ws = (char*)d_ws;
  u32* hist = (u32*)(ws + WS_HIST);
  u32* mcount = (u32*)(ws + WS_MCOUNT);
  u32* bcount = (u32*)(ws + WS_BCOUNT);
  u64* mainL = (u64*)(ws + WS_MAIN);
  u64* bndL = (u64*)(ws + WS_BND);
  float4* boxes = (float4*)(ws + WS_BOXES);
  int* cls = (int*)(ws + WS_CLS);
  float* score = (float*)(ws + WS_SCORE);
  u64* mask = (u64*)(ws + WS_MASK);
  float2* mrt = (float2*)(ws + WS_MRT);

  hipMemsetAsync(d_ws, 0, WS_ZERO_END, stream);
  k_score<<<NBLK_SC, SC_T, 0, stream>>>(logits, hist, mrt);
  k_emit<<<NBLK_SC, SC_T, 0, stream>>>(logits, mrt, hist, mainL, mcount, bndL, bcount);
  k_refine<<<28, 1024, 0, stream>>>(hist, bndL, bcount, mainL, mcount);
  k_gsel<<<NIMG, 1024, 0, stream>>>(hist, mainL, mcount, priors, reg, boxes, cls, score);
  k_mask<<<NIMG * 500, 256, 0, stream>>>(boxes, cls, mask);
  k_scanfinal<<<NIMG, 256, 0, stream>>>(mask, boxes, cls, score, (float*)d_out);
}

// Round 6
// 152.683 us; speedup vs baseline: 4.5433x; 1.1134x over previous
//
#include <hip/hip_runtime.h>
#include <hip/hip_bf16.h>
#include <math.h>

typedef unsigned long long u64;
typedef unsigned int u32;

#define A_TOTAL 24564
#define NCLS 80
#define NIMG 4
#define NPRE 2000
#define NLV 7
#define HBUCKETS 1024
#define BEXP_BASE 0x3CA3
#define TOTAL_G (NIMG * A_TOTAL)   // 98256
#define FA 64                      // anchors per block (fused/filter)
#define FT 256                     // threads per block
#define NBLK_F ((TOTAL_G + FA - 1) / FA)  // 1536
#define POOL_CAP_MAX 4096

__device__ __constant__ int c_klv[NLV] = {1000,1000,1000,1000,1000,1000,320};

// ---- workspace layout (bytes) ----
#define WS_HIST      0          // 28*1024*4 = 114688
#define WS_MCOUNT    114688     // 28*4
#define WS_BCOUNT    114800     // 28*4
#define WS_PCOUNT    114912     // 1536*4 = 6144
#define WS_ZERO_END  121056
#define WS_CUTS      121056     // 28*8 (overwritten every call)
#define WS_MAIN      121280     // 28*1024*8
#define WS_BND       350656     // 28*4096*8
#define WS_BOXES     1268160    // 4*2000*16
#define WS_CLS       1396160    // 4*2000*4
#define WS_SCORE     1428160    // 4*2000*4
#define WS_MASK      1460160    // 4*2000*32*8 = 2048000
#define WS_POOL      3508160    // NBLK_F * cap * 8, cap adaptive to ws_size

__device__ inline u64 shfl_u64(u64 v, int src) {
  int lo = __shfl((int)(u32)(v & 0xFFFFFFFFULL), src);
  int hi = __shfl((int)(u32)(v >> 32), src);
  return ((u64)(u32)hi << 32) | (u32)lo;
}

__device__ inline int score_bucket(u32 bits) {
  int b = (int)(bits >> 16) - BEXP_BASE;
  return b < 0 ? 0 : (b > HBUCKETS - 1 ? HBUCKETS - 1 : b);
}

__device__ inline int level_of(int a) {
  return (a < 16384) ? 0 : (a < 22528) ? 1 : (a < 24064) ? 2 :
         (a < 24448) ? 3 : (a < 24544) ? 4 : (a < 24560) ? 5 : 6;
}

// One full wave finds (cut bucket, count-in-bucket) for top-k over a 1024-bin
// histogram h. Deterministic: same h,k -> same result.
__device__ inline void wave_find_cut(const u32* __restrict__ h, int k, int lane,
                                     int& cx, int& cy) {
  u32 s = 0;
#pragma unroll
  for (int i = 0; i < 16; ++i) s += h[lane * 16 + i];
  u32 S = s;  // inclusive suffix-sum across lanes
#pragma unroll
  for (int o = 1; o < 64; o <<= 1) {
    u32 t = (u32)__shfl_down((int)S, o);
    if (lane + o < 64) S += t;
  }
  u32 total = (u32)__shfl((int)S, 0);
  if (total <= (u32)k) { cx = -1; cy = 0; return; }
  u64 bm = __ballot(S >= (u32)k);
  int L0 = 63 - (int)__clzll((long long)bm);
  u32 Sup = (u32)__shfl_down((int)S, 1);
  if (lane == 63) Sup = 0;
  int rcx = 0, rcy = 0;
  if (lane == L0) {
    u32 cum = Sup;
    for (int i = 15; i >= 0; --i) {
      u32 c = h[lane * 16 + i];
      if (cum + c >= (u32)k) { rcx = lane * 16 + i; rcy = k - (int)cum; break; }
      cum += c;
    }
  }
  cx = __shfl(rcx, L0);
  cy = __shfl(rcy, L0);
}

// Single scoring pass: LDS-staged softmax (4 threads/anchor), per-seg score
// histogram, and emission of ALL above-threshold keys into this block's
// private pool slice. No global atomics; one LDS counter, batched.
__global__ __launch_bounds__(FT) void k_fused(const float* __restrict__ logits,
                                              u32* __restrict__ histG,
                                              u64* __restrict__ pool,
                                              u32* __restrict__ pcount, int cap) {
  __shared__ float sx[FA * 81];   // 20736 B
  __shared__ u32 sh[HBUCKETS];    // 4096 B
  __shared__ int nm;
  int tid = threadIdx.x, bx = blockIdx.x;
  for (int b = tid; b < HBUCKETS; b += FT) sh[b] = 0;
  if (tid == 0) nm = 0;
  size_t base_f = (size_t)bx * (FA * 81);
  int cap4 = FA * 81 / 4;
  long long rem4 = ((long long)TOTAL_G * 81 - (long long)base_f) / 4;
  int n4 = (rem4 > cap4) ? cap4 : (int)rem4;
  const float4* src = (const float4*)(logits + base_f);
  float4* dst = (float4*)sx;
  for (int t = tid; t < n4; t += FT) dst[t] = src[t];
  __syncthreads();
  int la = tid >> 2, q = tid & 3;
  int g = bx * FA + la;
  bool valid = g < TOTAL_G;
  int g0 = bx * FA;
  int seg0 = (g0 / A_TOTAL) * NLV + level_of(g0 % A_TOTAL);
  int seg = seg0, a = 0;
  float e[20];
  float rt = 0.f;
  if (valid) {
    int img = g / A_TOTAL;
    a = g - img * A_TOTAL;
    seg = img * NLV + level_of(a);
    int rowoff = la * 81, c0 = q * 20;
    float mloc = sx[rowoff + c0];
#pragma unroll
    for (int i = 1; i < 20; ++i) mloc = fmaxf(mloc, sx[rowoff + c0 + i]);
    if (q == 3) mloc = fmaxf(mloc, sx[rowoff + 80]);
    float m = fmaxf(mloc, __shfl_xor(mloc, 1));
    m = fmaxf(m, __shfl_xor(m, 2));
    float tq = 0.f;
#pragma unroll
    for (int i = 0; i < 20; ++i) { e[i] = expf(sx[rowoff + c0 + i] - m); tq += e[i]; }
    if (q == 3) tq += expf(sx[rowoff + 80] - m);
    float t = tq + __shfl_xor(tq, 1);
    t = t + __shfl_xor(t, 2);
    rt = 1.0f / t;
  }
  int uniform = __syncthreads_and((int)(!valid || seg == seg0));
  if (valid) {
    u32* hdst = uniform ? sh : (histG + (size_t)seg * HBUCKETS);
    int c0 = q * 20;
    u32 wmask = 0;
#pragma unroll
    for (int i = 0; i < 20; ++i) {
      float s = e[i] * rt;
      if (s > 0.02f) wmask |= (1u << i);
    }
    int cnt = __popc(wmask);
    int basep = 0;
    if (cnt) basep = atomicAdd(&nm, cnt);
    while (wmask) {
      int i = __ffs(wmask) - 1;
      wmask &= wmask - 1;
      float s = e[i] * rt;
      u32 bits = __float_as_uint(s);
      atomicAdd(&hdst[score_bucket(bits)], 1u);
      if (basep < cap)
        pool[(size_t)bx * cap + basep] =
            ((u64)bits << 32) | (u64)(0xFFFFFFFFu - (u32)(a * NCLS + c0 + i));
      ++basep;
    }
  }
  __syncthreads();
  if (uniform) {
    u32* hseg = histG + (size_t)seg0 * HBUCKETS;
    for (int b = tid; b < HBUCKETS; b += FT) {
      u32 v = sh[b];
      if (v) atomicAdd(&hseg[b], v);
    }
  }
  if (tid == 0) pcount[bx] = (u32)nm;
}

__global__ __launch_bounds__(1024) void k_cuts(const u32* __restrict__ histG,
                                               int2* __restrict__ cutsG) {
  int wid = threadIdx.x >> 6, lane = threadIdx.x & 63;
  for (int seg = wid; seg < NIMG * NLV; seg += 16) {
    int cx, cy;
    wave_find_cut(histG + (size_t)seg * HBUCKETS, c_klv[seg % NLV], lane, cx, cy);
    if (lane == 0) cutsG[seg] = make_int2(cx, cy);
  }
}

// Stream this block's pool slice, keep above-cut/boundary entries.
// Fallback (pool overflow, statistically never): recompute the block's
// anchors from logits with bit-identical arithmetic.
__global__ __launch_bounds__(FT) void k_filter(const float* __restrict__ logits,
                                               const u64* __restrict__ pool,
                                               const u32* __restrict__ pcount,
                                               const int2* __restrict__ cutsG, int cap,
                                               u64* __restrict__ mainG, u32* __restrict__ mcount,
                                               u64* __restrict__ bndG, u32* __restrict__ bcount) {
  __shared__ float sx[FA * 81];
  __shared__ int2 scuts[NIMG * NLV];
  __shared__ u64 mk[1024]; __shared__ unsigned char msg_[1024];
  __shared__ u64 bkl[256]; __shared__ unsigned char bsg[256];
  __shared__ int nm, nb, cm[4], cb[4], basem[4], baseb[4], wm[4], wb[4];
  int tid = threadIdx.x, bx = blockIdx.x;
  if (tid < NIMG * NLV) scuts[tid] = cutsG[tid];
  if (tid < 4) { cm[tid] = 0; cb[tid] = 0; wm[tid] = 0; wb[tid] = 0; }
  if (tid == 0) { nm = 0; nb = 0; }
  int g0 = bx * FA;
  int img0 = g0 / A_TOTAL;
  int alo = g0 - img0 * A_TOTAL;
  int gN = g0 + FA - 1; if (gN > TOTAL_G - 1) gN = TOTAL_G - 1;
  int seg_lo = img0 * NLV + level_of(alo);
  int seg_hi = (gN / A_TOTAL) * NLV + level_of(gN % A_TOTAL);
  __syncthreads();
  int n = (int)pcount[bx];
  if (n <= cap) {
    for (int t = tid; t < n; t += FT) {
      u64 key = pool[(size_t)bx * cap + t];
      u32 bits = (u32)(key >> 32);
      u32 flat = 0xFFFFFFFFu - (u32)(key & 0xFFFFFFFFULL);
      int a = (int)(flat / NCLS);
      int img = (a >= alo) ? img0 : img0 + 1;
      int seg = img * NLV + level_of(a);
      int2 ct = scuts[seg];
      int bk = score_bucket(bits);
      int si = seg - seg_lo;
      if (ct.x < 0 || bk > ct.x) {
        int p = atomicAdd(&nm, 1);
        if (p < 1024) { mk[p] = key; msg_[p] = (unsigned char)si; atomicAdd(&cm[si], 1); }
        else { u32 pg = atomicAdd(&mcount[seg], 1u); if (pg < 1024) mainG[(size_t)seg * 1024 + pg] = key; }
      } else if (bk == ct.x) {
        int p = atomicAdd(&nb, 1);
        if (p < 256) { bkl[p] = key; bsg[p] = (unsigned char)si; atomicAdd(&cb[si], 1); }
        else { u32 pg = atomicAdd(&bcount[seg], 1u); if (pg < 4096) bndG[(size_t)seg * 4096 + pg] = key; }
      }
    }
  } else {
    size_t base_f = (size_t)bx * (FA * 81);
    int cap4 = FA * 81 / 4;
    long long rem4 = ((long long)TOTAL_G * 81 - (long long)base_f) / 4;
    int n4 = (rem4 > cap4) ? cap4 : (int)rem4;
    const float4* src = (const float4*)(logits + base_f);
    float4* dst = (float4*)sx;
    for (int t = tid; t < n4; t += FT) dst[t] = src[t];
    __syncthreads();
    int la = tid >> 2, q = tid & 3;
    int g = g0 + la;
    if (g < TOTAL_G) {
      int img = g / A_TOTAL;
      int a = g - img * A_TOTAL;
      int seg = img * NLV + level_of(a);
      int si = seg - seg_lo;
      int2 ct = scuts[seg];
      int rowoff = la * 81, c0 = q * 20;
      float mloc = sx[rowoff + c0];
#pragma unroll
      for (int i = 1; i < 20; ++i) mloc = fmaxf(mloc, sx[rowoff + c0 + i]);
      if (q == 3) mloc = fmaxf(mloc, sx[rowoff + 80]);
      float m = fmaxf(mloc, __shfl_xor(mloc, 1));
      m = fmaxf(m, __shfl_xor(m, 2));
      float tq = 0.f;
      float e[20];
#pragma unroll
      for (int i = 0; i < 20; ++i) { e[i] = expf(sx[rowoff + c0 + i] - m); tq += e[i]; }
      if (q == 3) tq += expf(sx[rowoff + 80] - m);
      float tt = tq + __shfl_xor(tq, 1);
      tt = tt + __shfl_xor(tt, 2);
      float rt = 1.0f / tt;
      for (int i = 0; i < 20; ++i) {
        float s = e[i] * rt;
        if (s > 0.02f) {
          u32 bits = __float_as_uint(s);
          int bk = score_bucket(bits);
          u64 key = ((u64)bits << 32) | (u64)(0xFFFFFFFFu - (u32)(a * NCLS + c0 + i));
          if (ct.x < 0 || bk > ct.x) {
            int p = atomicAdd(&nm, 1);
            if (p < 1024) { mk[p] = key; msg_[p] = (unsigned char)si; atomicAdd(&cm[si], 1); }
            else { u32 pg = atomicAdd(&mcount[seg], 1u); if (pg < 1024) mainG[(size_t)seg * 1024 + pg] = key; }
          } else if (bk == ct.x) {
            int p = atomicAdd(&nb, 1);
            if (p < 256) { bkl[p] = key; bsg[p] = (unsigned char)si; atomicAdd(&cb[si], 1); }
            else { u32 pg = atomicAdd(&bcount[seg], 1u); if (pg < 4096) bndG[(size_t)seg * 4096 + pg] = key; }
          }
        }
      }
    }
  }
  __syncthreads();
  if (tid <= seg_hi - seg_lo) {
    if (cm[tid] > 0) basem[tid] = (int)atomicAdd(&mcount[seg_lo + tid], (u32)cm[tid]);
    if (cb[tid] > 0) baseb[tid] = (int)atomicAdd(&bcount[seg_lo + tid], (u32)cb[tid]);
  }
  __syncthreads();
  int tm = nm < 1024 ? nm : 1024;
  for (int idx = tid; idx < tm; idx += FT) {
    int si = msg_[idx];
    int slot = atomicAdd(&wm[si], 1);
    int d = basem[si] + slot;
    if (d < 1024) mainG[(size_t)(seg_lo + si) * 1024 + d] = mk[idx];
  }
  int tb = nb < 256 ? nb : 256;
  for (int idx = tid; idx < tb; idx += FT) {
    int si = bsg[idx];
    int slot = atomicAdd(&wb[si], 1);
    int d = baseb[si] + slot;
    if (d < 4096) bndG[(size_t)(seg_lo + si) * 4096 + d] = bkl[idx];
  }
}

__device__ inline void bitonic_desc(u64* s, int n) {
  for (int k = 2; k <= n; k <<= 1)
    for (int j = k >> 1; j > 0; j >>= 1) {
      __syncthreads();
      for (int i = threadIdx.x; i < n; i += blockDim.x) {
        int l = i ^ j;
        if (l > i) {
          u64 a = s[i], b = s[l];
          if (((i & k) == 0) ? (a < b) : (a > b)) { s[i] = b; s[l] = a; }
        }
      }
    }
  __syncthreads();
}

// exact per-level top-k: sort only pow2ceil(boundary count) elements
__global__ __launch_bounds__(1024) void k_refine(const u32* __restrict__ histG,
                                                 const u64* __restrict__ bndG,
                                                 const u32* __restrict__ bcount,
                                                 u64* __restrict__ mainG, u32* __restrict__ mcount) {
  int seg = blockIdx.x;
  __shared__ int sh_cx, sh_cy;
  __shared__ u64 s[4096];
  int tid = threadIdx.x, lane = tid & 63;
  if (tid < 64) {
    int cx, cy;
    wave_find_cut(histG + (size_t)seg * HBUCKETS, c_klv[seg % NLV], lane, cx, cy);
    if (lane == 0) { sh_cx = cx; sh_cy = cy; }
  }
  __syncthreads();
  if (sh_cx < 0) return;
  int m = (int)bcount[seg]; if (m > 4096) m = 4096;
  int n = 64; while (n < m) n <<= 1;
  for (int t = tid; t < n; t += 1024)
    s[t] = (t < m) ? bndG[(size_t)seg * 4096 + t] : 0ULL;
  bitonic_desc(s, n);
  int kp = sh_cy; if (kp > m) kp = m;
  int base = (int)mcount[seg];
  for (int t = tid; t < kp; t += 1024) {
    int p = base + t;
    if (p < 1024) mainG[(size_t)seg * 1024 + p] = s[t];
  }
  __syncthreads();
  if (tid == 0) {
    int nb = base + kp;
    mcount[seg] = (u32)(nb > 1024 ? 1024 : nb);
  }
}

// per-image: global cut from truncated per-level histograms, compact <2000
// above-cut, sort tiny boundary, one 2048 bitonic, decode inline.
__global__ __launch_bounds__(1024) void k_gsel(const u32* __restrict__ histG,
                                               const u64* __restrict__ mainG,
                                               const u32* __restrict__ mcount,
                                               const float4* __restrict__ priors,
                                               const float4* __restrict__ reg,
                                               float4* __restrict__ boxesG,
                                               int* __restrict__ clsG,
                                               float* __restrict__ scoreG) {
  int img = blockIdx.x;
  int tid = threadIdx.x, wid = tid >> 6, lane = tid & 63;
  __shared__ u32 H[HBUCKETS];
  __shared__ int lcx[NLV], lcy[NLV];
  __shared__ int sh_gx, sh_gy, sh_m, sh_b;
  __shared__ u64 bnd2[4096];
  __shared__ u64 sel[2048];
  if (tid == 0) { sh_m = 0; sh_b = 0; }
  if (wid < NLV) {
    int cx, cy;
    wave_find_cut(histG + (size_t)(img * NLV + wid) * HBUCKETS, c_klv[wid], lane, cx, cy);
    if (lane == 0) { lcx[wid] = cx; lcy[wid] = cy; }
  }
  __syncthreads();
  for (int b = tid; b < HBUCKETS; b += 1024) {
    u32 acc = 0;
#pragma unroll
    for (int l = 0; l < NLV; ++l) {
      u32 h = histG[(size_t)(img * NLV + l) * HBUCKETS + b];
      int cx = lcx[l];
      if (cx < 0 || b > cx) acc += h;
      else if (b == cx) acc += (u32)lcy[l];
    }
    H[b] = acc;
  }
  __syncthreads();
  if (wid == 0) {
    int gx, gy;
    wave_find_cut(H, NPRE, lane, gx, gy);
    if (lane == 0) { sh_gx = gx; sh_gy = gy; }
  }
  __syncthreads();
  int gx = sh_gx, gy = sh_gy;
  for (int l = 0; l < NLV; ++l) {
    int cnt = (int)mcount[img * NLV + l]; if (cnt > 1024) cnt = 1024;
    for (int t = tid; t < cnt; t += 1024) {
      u64 key = mainG[(size_t)(img * NLV + l) * 1024 + t];
      int b = (int)(key >> 48) - BEXP_BASE;
      b = b < 0 ? 0 : (b > HBUCKETS - 1 ? HBUCKETS - 1 : b);
      if (gx < 0 || b > gx) { int p = atomicAdd(&sh_m, 1); if (p < 2048) sel[p] = key; }
      else if (b == gx)     { int p = atomicAdd(&sh_b, 1); if (p < 4096) bnd2[p] = key; }
    }
  }
  __syncthreads();
  int msel = sh_m; if (msel > 2048) msel = 2048;
  int nb = sh_b; if (nb > 4096) nb = 4096;
  int take = 0;
  if (gx >= 0) {
    int n = 64; while (n < nb) n <<= 1;
    for (int t = tid; t < n; t += 1024) if (t >= nb) bnd2[t] = 0ULL;
    bitonic_desc(bnd2, n);
    take = gy; if (take > nb) take = nb;
    if (msel + take > 2048) take = 2048 - msel;
    for (int t = tid; t < take; t += 1024) sel[msel + t] = bnd2[t];
  }
  int tot = msel + take;
  for (int t = tid; t < 2048; t += 1024) if (t >= tot) sel[t] = 0ULL;
  bitonic_desc(sel, 2048);
  for (int t = tid; t < NPRE; t += 1024) {
    u64 key = sel[t];
    float4 bx = make_float4(0.f, 0.f, 0.f, 0.f);
    int c = -1;
    float sc = 0.f;
    if (key != 0ULL) {
      sc = __uint_as_float((u32)(key >> 32));
      u32 flat = 0xFFFFFFFFu - (u32)(key & 0xFFFFFFFFULL);
      int a = (int)(flat / NCLS);
      c = (int)(flat % NCLS);
      float4 p = priors[a];
      float4 r = reg[(size_t)img * A_TOTAL + a];
      float cx = p.x + (r.x * 0.1f) * p.z;
      float cy = p.y + (r.y * 0.1f) * p.w;
      float w = p.z * expf(r.z * 0.2f);
      float h = p.w * expf(r.w * 0.2f);
      bx.x = fminf(fmaxf(cx - w * 0.5f, 0.f), 512.f);
      bx.y = fminf(fmaxf(cy - h * 0.5f, 0.f), 512.f);
      bx.z = fminf(fmaxf(cx + w * 0.5f, 0.f), 512.f);
      bx.w = fminf(fmaxf(cy + h * 0.5f, 0.f), 512.f);
    }
    boxesG[(size_t)img * NPRE + t] = bx;
    clsG[(size_t)img * NPRE + t] = c;
    scoreG[(size_t)img * NPRE + t] = sc;
  }
}

// suppression bitmask: row i, bit j set iff j>i, same class, IoU>0.45
__global__ __launch_bounds__(256) void k_mask(const float4* __restrict__ boxesG,
                                              const int* __restrict__ clsG,
                                              u64* __restrict__ maskG) {
  __shared__ float4 lb[NPRE];
  __shared__ int lc[NPRE];
  int img = blockIdx.x / 500;
  int rb = (blockIdx.x % 500) * 4;
  for (int t = threadIdx.x; t < NPRE; t += 256) {
    lb[t] = boxesG[(size_t)img * NPRE + t];
    lc[t] = clsG[(size_t)img * NPRE + t];
  }
  __syncthreads();
  int w = threadIdx.x >> 6, lane = threadIdx.x & 63;
  int i = rb + w;
  float4 bi = lb[i];
  int ci = lc[i];
  float ai = (bi.z - bi.x) * (bi.w - bi.y);
  u64* mrow = maskG + ((size_t)img * NPRE + i) * 32;
  for (int ch = 0; ch < 32; ++ch) {
    int j = ch * 64 + lane;
    bool pred = false;
    if (j < NPRE && j > i) {
      if (lc[j] == ci) {
        float4 bj = lb[j];
        float xx1 = fmaxf(bi.x, bj.x), yy1 = fmaxf(bi.y, bj.y);
        float xx2 = fminf(bi.z, bj.z), yy2 = fminf(bi.w, bj.w);
        float ww = fmaxf(xx2 - xx1, 0.f), hh = fmaxf(yy2 - yy1, 0.f);
        float inter = ww * hh;
        float aj = (bj.z - bj.x) * (bj.w - bj.y);
        float iou = inter / fmaxf(ai + aj - inter, 1e-6f);
        pred = iou > 0.45f;
      }
    }
    u64 word = __ballot(pred);
    if (lane == 0) mrow[ch] = word;
  }
}

// greedy scan with early exit at 200 kept, fused with final gather.
__global__ __launch_bounds__(256) void k_scanfinal(const u64* __restrict__ maskG,
                                                   const float4* __restrict__ boxesG,
                                                   const int* __restrict__ clsG,
                                                   const float* __restrict__ scoreG,
                                                   float* __restrict__ out) {
  int img = blockIdx.x;
  int tid = threadIdx.x;
  __shared__ u64 sh_remv[32];
  __shared__ u32 keptList[216];
  __shared__ int sh_cnt, sh_done;
  __shared__ int kpref[257];
  __shared__ unsigned short S[NPRE];
  if (tid == 0) { sh_cnt = 0; sh_done = 0; }
  __syncthreads();
  if (tid < 64) {
    int lane = tid;
    int wl = lane & 31;
    const u64* M = maskG + (size_t)img * NPRE * 32;
    u64 remv = 0;
    u64 cur[16], nxt[16];
    int cnt = 0;
#pragma unroll
    for (int r = 0; r < 16; ++r) cur[r] = M[(size_t)r * 32 + wl];
    int t = 0;
    for (; t < 125; ++t) {
      if (t < 124) {
#pragma unroll
        for (int r = 0; r < 16; ++r) nxt[r] = M[(size_t)((t + 1) * 16 + r) * 32 + wl];
      }
#pragma unroll
      for (int r = 0; r < 16; ++r) {
        int i = t * 16 + r;
        u64 rm = shfl_u64(remv, i >> 6);
        if (!((rm >> (i & 63)) & 1ULL)) {
          remv |= cur[r];
          if (lane == 0 && cnt < 216) keptList[cnt] = (u32)i;
          ++cnt;
        }
      }
#pragma unroll
      for (int r = 0; r < 16; ++r) cur[r] = nxt[r];
      if (cnt >= 200) { ++t; break; }
    }
    if (lane == 0) sh_cnt = cnt < 216 ? cnt : 216;
    if (t >= 125) {
      if (lane == 0) sh_done = 1;
      if (lane < 32) sh_remv[lane] = remv;
    }
  }
  __syncthreads();
  int nK = sh_cnt;
  if (sh_done && nK < 200) {
    int base = tid * 8;
    bool sb[8];
    int scnt = 0;
#pragma unroll
    for (int e = 0; e < 8; ++e) {
      int i = base + e;
      bool sup = (i < NPRE) && ((sh_remv[i >> 6] >> (i & 63)) & 1ULL);
      sb[e] = sup;
      scnt += sup ? 1 : 0;
    }
    kpref[tid + 1] = scnt;
    if (tid == 0) kpref[0] = 0;
    __syncthreads();
    if (tid == 0) {
      int acc = 0;
      for (int t = 1; t <= 256; ++t) { acc += kpref[t]; kpref[t] = acc; }
    }
    __syncthreads();
    int sp = kpref[tid];
#pragma unroll
    for (int e = 0; e < 8; ++e) {
      int i = base + e;
      if (i < NPRE && sb[e]) S[sp++] = (unsigned short)i;
    }
    __syncthreads();
    if (tid < 200) {
      float fv = 0.f;
      float4 fb = make_float4(0.f, 0.f, 0.f, 0.f);
      int fc;
      if (tid < nK) {
        int idx = (int)keptList[tid];
        fv = scoreG[(size_t)img * NPRE + idx];
        fb = boxesG[(size_t)img * NPRE + idx];
        fc = clsG[(size_t)img * NPRE + idx];
      } else {
        int idx = S[tid - nK];
        fc = clsG[(size_t)img * NPRE + idx];
      }
      float* fbo = out + (size_t)img * 800 + tid * 4;
      fbo[0] = fb.x; fbo[1] = fb.y; fbo[2] = fb.z; fbo[3] = fb.w;
      out[3200 + (size_t)img * 200 + tid] = fv;
      out[4000 + (size_t)img * 200 + tid] = (float)fc;
    }
  } else {
    if (tid < 200) {
      int idx = (int)keptList[tid];
      float fv = scoreG[(size_t)img * NPRE + idx];
      float4 fb = boxesG[(size_t)img * NPRE + idx];
      int fc = clsG[(size_t)img * NPRE + idx];
      float* fbo = out + (size_t)img * 800 + tid * 4;
      fbo[0] = fb.x; fbo[1] = fb.y; fbo[2] = fb.z; fbo[3] = fb.w;
      out[3200 + (size_t)img * 200 + tid] = fv;
      out[4000 + (size_t)img * 200 + tid] = (float)fc;
    }
  }
}

extern "C" void kernel_launch(void* const* d_in, const int* in_sizes, int n_in,
                              void* d_out, int out_size, void* d_ws, size_t ws_size,
                              hipStream_t stream) {
  const float* logits = (const float*)d_in[0];
  const float4* reg = (const float4*)d_in[1];
  const float4* priors = (const float4*)d_in[2];
  char* ws = (char*)d_ws;
  u32* hist = (u32*)(ws + WS_HIST);
  u32* mcount = (u32*)(ws + WS_MCOUNT);
  u32* bcount = (u32*)(ws + WS_BCOUNT);
  u32* pcount = (u32*)(ws + WS_PCOUNT);
  int2* cuts = (int2*)(ws + WS_CUTS);
  u64* mainL = (u64*)(ws + WS_MAIN);
  u64* bndL = (u64*)(ws + WS_BND);
  float4* boxes = (float4*)(ws + WS_BOXES);
  int* cls = (int*)(ws + WS_CLS);
  float* score = (float*)(ws + WS_SCORE);
  u64* mask = (u64*)(ws + WS_MASK);
  u64* pool = (u64*)(ws + WS_POOL);

  size_t avail = ws_size > (size_t)WS_POOL ? ws_size - (size_t)WS_POOL : 0;
  int cap = (int)(avail / ((size_t)NBLK_F * 8));
  if (cap > POOL_CAP_MAX) cap = POOL_CAP_MAX;

  hipMemsetAsync(d_ws, 0, WS_ZERO_END, stream);
  k_fused<<<NBLK_F, FT, 0, stream>>>(logits, hist, pool, pcount, cap);
  k_cuts<<<1, 1024, 0, stream>>>(hist, cuts);
  k_filter<<<NBLK_F, FT, 0, stream>>>(logits, pool, pcount, cuts, cap,
                                      mainL, mcount, bndL, bcount);
  k_refine<<<28, 1024, 0, stream>>>(hist, bndL, bcount, mainL, mcount);
  k_gsel<<<NIMG, 1024, 0, stream>>>(hist, mainL, mcount, priors, reg, boxes, cls, score);
  k_mask<<<NIMG * 500, 256, 0, stream>>>(boxes, cls, mask);
  k_scanfinal<<<NIMG, 256, 0, stream>>>(mask, boxes, cls, score, (float*)d_out);
}

// Round 7
// 123.572 us; speedup vs baseline: 5.6137x; 1.2356x over previous
//
#include <hip/hip_runtime.h>
#include <hip/hip_bf16.h>
#include <math.h>

typedef unsigned long long u64;
typedef unsigned int u32;

#define A_TOTAL 24564
#define NCLS 80
#define NIMG 4
#define NPRE 2000
#define NLV 7
#define HBUCKETS 1024
#define BEXP_BASE 0x3CA3
#define TOTAL_G (NIMG * A_TOTAL)   // 98256
#define FA 64                      // anchors per block (fused/filter)
#define FT 256                     // threads per block
#define NBLK_F ((TOTAL_G + FA - 1) / FA)  // 1536
#define POOL_CAP_MAX 4096
#define CAPSEL 4608

__device__ __constant__ int c_klv[NLV] = {1000,1000,1000,1000,1000,1000,320};

// ---- workspace layout (bytes) ----
#define WS_HIST      0          // 28*1024*4 = 114688
#define WS_MCOUNT    114688     // 28*4
#define WS_BCOUNT    114800     // 28*4
#define WS_PCOUNT    114912     // 1536*4 = 6144
#define WS_ZERO_END  121056
#define WS_CUTS      121056     // 28*8 (overwritten every call)
#define WS_MAIN      121280     // 28*1024*8
#define WS_BND       350656     // 28*4096*8
#define WS_BOXES     1268160    // 4*2000*16
#define WS_CLS       1396160    // 4*2000*4
#define WS_SCORE     1428160    // 4*2000*4
#define WS_MASK      1460160    // 4*2000*32*8 = 2048000
#define WS_POOL      3508160    // NBLK_F * cap * 8, cap adaptive to ws_size

__device__ inline u64 shfl_u64(u64 v, int src) {
  int lo = __shfl((int)(u32)(v & 0xFFFFFFFFULL), src);
  int hi = __shfl((int)(u32)(v >> 32), src);
  return ((u64)(u32)hi << 32) | (u32)lo;
}

__device__ inline int score_bucket(u32 bits) {
  int b = (int)(bits >> 16) - BEXP_BASE;
  return b < 0 ? 0 : (b > HBUCKETS - 1 ? HBUCKETS - 1 : b);
}

__device__ inline int level_of(int a) {
  return (a < 16384) ? 0 : (a < 22528) ? 1 : (a < 24064) ? 2 :
         (a < 24448) ? 3 : (a < 24544) ? 4 : (a < 24560) ? 5 : 6;
}

// One full wave finds (cut bucket, count-in-bucket) for top-k over a 1024-bin
// histogram h. Deterministic: same h,k -> same result.
__device__ inline void wave_find_cut(const u32* __restrict__ h, int k, int lane,
                                     int& cx, int& cy) {
  u32 s = 0;
#pragma unroll
  for (int i = 0; i < 16; ++i) s += h[lane * 16 + i];
  u32 S = s;  // inclusive suffix-sum across lanes
#pragma unroll
  for (int o = 1; o < 64; o <<= 1) {
    u32 t = (u32)__shfl_down((int)S, o);
    if (lane + o < 64) S += t;
  }
  u32 total = (u32)__shfl((int)S, 0);
  if (total <= (u32)k) { cx = -1; cy = 0; return; }
  u64 bm = __ballot(S >= (u32)k);
  int L0 = 63 - (int)__clzll((long long)bm);
  u32 Sup = (u32)__shfl_down((int)S, 1);
  if (lane == 63) Sup = 0;
  int rcx = 0, rcy = 0;
  if (lane == L0) {
    u32 cum = Sup;
    for (int i = 15; i >= 0; --i) {
      u32 c = h[lane * 16 + i];
      if (cum + c >= (u32)k) { rcx = lane * 16 + i; rcy = k - (int)cum; break; }
      cum += c;
    }
  }
  cx = __shfl(rcx, L0);
  cy = __shfl(rcy, L0);
}

// Single scoring pass: LDS-staged softmax (4 threads/anchor), per-seg score
// histogram, and emission of ALL above-threshold keys into this block's
// private pool slice. No global atomics; one LDS counter, batched.
__global__ __launch_bounds__(FT) void k_fused(const float* __restrict__ logits,
                                              u32* __restrict__ histG,
                                              u64* __restrict__ pool,
                                              u32* __restrict__ pcount, int cap) {
  __shared__ float sx[FA * 81];   // 20736 B
  __shared__ u32 sh[HBUCKETS];    // 4096 B
  __shared__ int nm;
  int tid = threadIdx.x, bx = blockIdx.x;
  for (int b = tid; b < HBUCKETS; b += FT) sh[b] = 0;
  if (tid == 0) nm = 0;
  size_t base_f = (size_t)bx * (FA * 81);
  int cap4 = FA * 81 / 4;
  long long rem4 = ((long long)TOTAL_G * 81 - (long long)base_f) / 4;
  int n4 = (rem4 > cap4) ? cap4 : (int)rem4;
  const float4* src = (const float4*)(logits + base_f);
  float4* dst = (float4*)sx;
  for (int t = tid; t < n4; t += FT) dst[t] = src[t];
  __syncthreads();
  int la = tid >> 2, q = tid & 3;
  int g = bx * FA + la;
  bool valid = g < TOTAL_G;
  int g0 = bx * FA;
  int seg0 = (g0 / A_TOTAL) * NLV + level_of(g0 % A_TOTAL);
  int seg = seg0, a = 0;
  float e[20];
  float rt = 0.f;
  if (valid) {
    int img = g / A_TOTAL;
    a = g - img * A_TOTAL;
    seg = img * NLV + level_of(a);
    int rowoff = la * 81, c0 = q * 20;
    float mloc = sx[rowoff + c0];
#pragma unroll
    for (int i = 1; i < 20; ++i) mloc = fmaxf(mloc, sx[rowoff + c0 + i]);
    if (q == 3) mloc = fmaxf(mloc, sx[rowoff + 80]);
    float m = fmaxf(mloc, __shfl_xor(mloc, 1));
    m = fmaxf(m, __shfl_xor(m, 2));
    float tq = 0.f;
#pragma unroll
    for (int i = 0; i < 20; ++i) { e[i] = expf(sx[rowoff + c0 + i] - m); tq += e[i]; }
    if (q == 3) tq += expf(sx[rowoff + 80] - m);
    float t = tq + __shfl_xor(tq, 1);
    t = t + __shfl_xor(t, 2);
    rt = 1.0f / t;
  }
  int uniform = __syncthreads_and((int)(!valid || seg == seg0));
  if (valid) {
    u32* hdst = uniform ? sh : (histG + (size_t)seg * HBUCKETS);
    int c0 = q * 20;
    u32 wmask = 0;
#pragma unroll
    for (int i = 0; i < 20; ++i) {
      float s = e[i] * rt;
      if (s > 0.02f) wmask |= (1u << i);
    }
    int cnt = __popc(wmask);
    int basep = 0;
    if (cnt) basep = atomicAdd(&nm, cnt);
    while (wmask) {
      int i = __ffs(wmask) - 1;
      wmask &= wmask - 1;
      float s = e[i] * rt;
      u32 bits = __float_as_uint(s);
      atomicAdd(&hdst[score_bucket(bits)], 1u);
      if (basep < cap)
        pool[(size_t)bx * cap + basep] =
            ((u64)bits << 32) | (u64)(0xFFFFFFFFu - (u32)(a * NCLS + c0 + i));
      ++basep;
    }
  }
  __syncthreads();
  if (uniform) {
    u32* hseg = histG + (size_t)seg0 * HBUCKETS;
    for (int b = tid; b < HBUCKETS; b += FT) {
      u32 v = sh[b];
      if (v) atomicAdd(&hseg[b], v);
    }
  }
  if (tid == 0) pcount[bx] = (u32)nm;
}

__global__ __launch_bounds__(1024) void k_cuts(const u32* __restrict__ histG,
                                               int2* __restrict__ cutsG) {
  int wid = threadIdx.x >> 6, lane = threadIdx.x & 63;
  for (int seg = wid; seg < NIMG * NLV; seg += 16) {
    int cx, cy;
    wave_find_cut(histG + (size_t)seg * HBUCKETS, c_klv[seg % NLV], lane, cx, cy);
    if (lane == 0) cutsG[seg] = make_int2(cx, cy);
  }
}

// Stream this block's pool slice, keep above-cut/boundary entries.
// Fallback (pool overflow, statistically never): recompute the block's
// anchors from logits with bit-identical arithmetic.
__global__ __launch_bounds__(FT) void k_filter(const float* __restrict__ logits,
                                               const u64* __restrict__ pool,
                                               const u32* __restrict__ pcount,
                                               const int2* __restrict__ cutsG, int cap,
                                               u64* __restrict__ mainG, u32* __restrict__ mcount,
                                               u64* __restrict__ bndG, u32* __restrict__ bcount) {
  __shared__ float sx[FA * 81];
  __shared__ int2 scuts[NIMG * NLV];
  __shared__ u64 mk[1024]; __shared__ unsigned char msg_[1024];
  __shared__ u64 bkl[256]; __shared__ unsigned char bsg[256];
  __shared__ int nm, nb, cm[4], cb[4], basem[4], baseb[4], wm[4], wb[4];
  int tid = threadIdx.x, bx = blockIdx.x;
  if (tid < NIMG * NLV) scuts[tid] = cutsG[tid];
  if (tid < 4) { cm[tid] = 0; cb[tid] = 0; wm[tid] = 0; wb[tid] = 0; }
  if (tid == 0) { nm = 0; nb = 0; }
  int g0 = bx * FA;
  int img0 = g0 / A_TOTAL;
  int alo = g0 - img0 * A_TOTAL;
  int gN = g0 + FA - 1; if (gN > TOTAL_G - 1) gN = TOTAL_G - 1;
  int seg_lo = img0 * NLV + level_of(alo);
  int seg_hi = (gN / A_TOTAL) * NLV + level_of(gN % A_TOTAL);
  __syncthreads();
  int n = (int)pcount[bx];
  if (n <= cap) {
    for (int t = tid; t < n; t += FT) {
      u64 key = pool[(size_t)bx * cap + t];
      u32 bits = (u32)(key >> 32);
      u32 flat = 0xFFFFFFFFu - (u32)(key & 0xFFFFFFFFULL);
      int a = (int)(flat / NCLS);
      int img = (a >= alo) ? img0 : img0 + 1;
      int seg = img * NLV + level_of(a);
      int2 ct = scuts[seg];
      int bk = score_bucket(bits);
      int si = seg - seg_lo;
      if (ct.x < 0 || bk > ct.x) {
        int p = atomicAdd(&nm, 1);
        if (p < 1024) { mk[p] = key; msg_[p] = (unsigned char)si; atomicAdd(&cm[si], 1); }
        else { u32 pg = atomicAdd(&mcount[seg], 1u); if (pg < 1024) mainG[(size_t)seg * 1024 + pg] = key; }
      } else if (bk == ct.x) {
        int p = atomicAdd(&nb, 1);
        if (p < 256) { bkl[p] = key; bsg[p] = (unsigned char)si; atomicAdd(&cb[si], 1); }
        else { u32 pg = atomicAdd(&bcount[seg], 1u); if (pg < 4096) bndG[(size_t)seg * 4096 + pg] = key; }
      }
    }
  } else {
    size_t base_f = (size_t)bx * (FA * 81);
    int cap4 = FA * 81 / 4;
    long long rem4 = ((long long)TOTAL_G * 81 - (long long)base_f) / 4;
    int n4 = (rem4 > cap4) ? cap4 : (int)rem4;
    const float4* src = (const float4*)(logits + base_f);
    float4* dst = (float4*)sx;
    for (int t = tid; t < n4; t += FT) dst[t] = src[t];
    __syncthreads();
    int la = tid >> 2, q = tid & 3;
    int g = g0 + la;
    if (g < TOTAL_G) {
      int img = g / A_TOTAL;
      int a = g - img * A_TOTAL;
      int seg = img * NLV + level_of(a);
      int si = seg - seg_lo;
      int2 ct = scuts[seg];
      int rowoff = la * 81, c0 = q * 20;
      float mloc = sx[rowoff + c0];
#pragma unroll
      for (int i = 1; i < 20; ++i) mloc = fmaxf(mloc, sx[rowoff + c0 + i]);
      if (q == 3) mloc = fmaxf(mloc, sx[rowoff + 80]);
      float m = fmaxf(mloc, __shfl_xor(mloc, 1));
      m = fmaxf(m, __shfl_xor(m, 2));
      float tq = 0.f;
      float e[20];
#pragma unroll
      for (int i = 0; i < 20; ++i) { e[i] = expf(sx[rowoff + c0 + i] - m); tq += e[i]; }
      if (q == 3) tq += expf(sx[rowoff + 80] - m);
      float tt = tq + __shfl_xor(tq, 1);
      tt = tt + __shfl_xor(tt, 2);
      float rt = 1.0f / tt;
      for (int i = 0; i < 20; ++i) {
        float s = e[i] * rt;
        if (s > 0.02f) {
          u32 bits = __float_as_uint(s);
          int bk = score_bucket(bits);
          u64 key = ((u64)bits << 32) | (u64)(0xFFFFFFFFu - (u32)(a * NCLS + c0 + i));
          if (ct.x < 0 || bk > ct.x) {
            int p = atomicAdd(&nm, 1);
            if (p < 1024) { mk[p] = key; msg_[p] = (unsigned char)si; atomicAdd(&cm[si], 1); }
            else { u32 pg = atomicAdd(&mcount[seg], 1u); if (pg < 1024) mainG[(size_t)seg * 1024 + pg] = key; }
          } else if (bk == ct.x) {
            int p = atomicAdd(&nb, 1);
            if (p < 256) { bkl[p] = key; bsg[p] = (unsigned char)si; atomicAdd(&cb[si], 1); }
            else { u32 pg = atomicAdd(&bcount[seg], 1u); if (pg < 4096) bndG[(size_t)seg * 4096 + pg] = key; }
          }
        }
      }
    }
  }
  __syncthreads();
  if (tid <= seg_hi - seg_lo) {
    if (cm[tid] > 0) basem[tid] = (int)atomicAdd(&mcount[seg_lo + tid], (u32)cm[tid]);
    if (cb[tid] > 0) baseb[tid] = (int)atomicAdd(&bcount[seg_lo + tid], (u32)cb[tid]);
  }
  __syncthreads();
  int tm = nm < 1024 ? nm : 1024;
  for (int idx = tid; idx < tm; idx += FT) {
    int si = msg_[idx];
    int slot = atomicAdd(&wm[si], 1);
    int d = basem[si] + slot;
    if (d < 1024) mainG[(size_t)(seg_lo + si) * 1024 + d] = mk[idx];
  }
  int tb = nb < 256 ? nb : 256;
  for (int idx = tid; idx < tb; idx += FT) {
    int si = bsg[idx];
    int slot = atomicAdd(&wb[si], 1);
    int d = baseb[si] + slot;
    if (d < 4096) bndG[(size_t)(seg_lo + si) * 4096 + d] = bkl[idx];
  }
}

__device__ inline void bitonic_desc(u64* s, int n) {
  for (int k = 2; k <= n; k <<= 1)
    for (int j = k >> 1; j > 0; j >>= 1) {
      __syncthreads();
      for (int i = threadIdx.x; i < n; i += blockDim.x) {
        int l = i ^ j;
        if (l > i) {
          u64 a = s[i], b = s[l];
          if (((i & k) == 0) ? (a < b) : (a > b)) { s[i] = b; s[l] = a; }
        }
      }
    }
  __syncthreads();
}

// exact per-level top-k: sort only pow2ceil(boundary count) elements
__global__ __launch_bounds__(1024) void k_refine(const u32* __restrict__ histG,
                                                 const u64* __restrict__ bndG,
                                                 const u32* __restrict__ bcount,
                                                 u64* __restrict__ mainG, u32* __restrict__ mcount) {
  int seg = blockIdx.x;
  __shared__ int sh_cx, sh_cy;
  __shared__ u64 s[4096];
  int tid = threadIdx.x, lane = tid & 63;
  if (tid < 64) {
    int cx, cy;
    wave_find_cut(histG + (size_t)seg * HBUCKETS, c_klv[seg % NLV], lane, cx, cy);
    if (lane == 0) { sh_cx = cx; sh_cy = cy; }
  }
  __syncthreads();
  if (sh_cx < 0) return;
  int m = (int)bcount[seg]; if (m > 4096) m = 4096;
  int n = 64; while (n < m) n <<= 1;
  for (int t = tid; t < n; t += 1024)
    s[t] = (t < m) ? bndG[(size_t)seg * 4096 + t] : 0ULL;
  bitonic_desc(s, n);
  int kp = sh_cy; if (kp > m) kp = m;
  int base = (int)mcount[seg];
  for (int t = tid; t < kp; t += 1024) {
    int p = base + t;
    if (p < 1024) mainG[(size_t)seg * 1024 + p] = s[t];
  }
  __syncthreads();
  if (tid == 0) {
    int nb = base + kp;
    mcount[seg] = (u32)(nb > 1024 ? 1024 : nb);
  }
}

// per-image: global cut from truncated per-level histograms, then histogram
// RANK-SORT (no bitonic): count per bucket -> suffix-scan bases -> scatter
// into bucket segments -> exact in-bucket rank by LDS scan -> permute in
// place. First NPRE positions = exact sorted top-2000. Decode inline.
__global__ __launch_bounds__(1024) void k_gsel(const u32* __restrict__ histG,
                                               const u64* __restrict__ mainG,
                                               const u32* __restrict__ mcount,
                                               const float4* __restrict__ priors,
                                               const float4* __restrict__ reg,
                                               float4* __restrict__ boxesG,
                                               int* __restrict__ clsG,
                                               float* __restrict__ scoreG) {
  int img = blockIdx.x;
  int tid = threadIdx.x, wid = tid >> 6, lane = tid & 63;
  __shared__ u32 H[HBUCKETS];     // merged hist; then scan pong; then subhist
  __shared__ u32 cntb[HBUCKETS];
  __shared__ u32 Sarr[HBUCKETS];  // inclusive suffix sums
  __shared__ u32 cnt2[HBUCKETS];
  __shared__ u64 sel[CAPSEL];     // 36864 B
  __shared__ int lcx[NLV], lcy[NLV];
  __shared__ int sh_gx, sh_gy, sh_cC, sh_cand, sh_sgx;
  if (tid == 0) { sh_cC = 0; sh_cand = 0; sh_sgx = -1; }
  if (wid < NLV) {
    int cx, cy;
    wave_find_cut(histG + (size_t)(img * NLV + wid) * HBUCKETS, c_klv[wid], lane, cx, cy);
    if (lane == 0) { lcx[wid] = cx; lcy[wid] = cy; }
  }
  __syncthreads();
  for (int b = tid; b < HBUCKETS; b += 1024) {
    u32 acc = 0;
#pragma unroll
    for (int l = 0; l < NLV; ++l) {
      u32 h = histG[(size_t)(img * NLV + l) * HBUCKETS + b];
      int cx = lcx[l];
      if (cx < 0 || b > cx) acc += h;
      else if (b == cx) acc += (u32)lcy[l];
    }
    H[b] = acc;
    cntb[b] = 0;
    cnt2[b] = 0;
  }
  __syncthreads();
  if (wid == 0) {
    int gx, gy;
    wave_find_cut(H, NPRE, lane, gx, gy);
    if (lane == 0) { sh_gx = gx; sh_gy = gy; }
  }
  __syncthreads();
  int gx = sh_gx, gy = sh_gy;
  int mcap[NLV];
#pragma unroll
  for (int l = 0; l < NLV; ++l) { int c = (int)mcount[img * NLV + l]; mcap[l] = c > 1024 ? 1024 : c; }
  // count pass
  for (int l = 0; l < NLV; ++l)
    for (int t = tid; t < mcap[l]; t += 1024) {
      u64 key = mainG[(size_t)(img * NLV + l) * 1024 + t];
      int b = score_bucket((u32)(key >> 32));
      if (gx < 0 || b > gx) atomicAdd(&cntb[b], 1u);
      else if (b == gx) atomicAdd(&sh_cC, 1);
    }
  __syncthreads();
  // inclusive suffix scan cntb -> Sarr (ping-pong with H; 10 steps -> Sarr)
  for (int b = tid; b < HBUCKETS; b += 1024) Sarr[b] = cntb[b];
  __syncthreads();
  {
    u32* A = Sarr; u32* B = H;
    for (int o = 1; o < HBUCKETS; o <<= 1) {
      for (int b = tid; b < HBUCKETS; b += 1024)
        B[b] = A[b] + ((b + o < HBUCKETS) ? A[b + o] : 0u);
      __syncthreads();
      u32* tmp = A; A = B; B = tmp;
    }
  }
  int cA = (int)Sarr[0];
  int cC = sh_cC;
  int cand = (gx >= 0) ? cC : 0;
  int sgx = -1;
  if (gx >= 0 && cA + cC > CAPSEL) {
    // sub-refine cut bucket by next 10 mantissa bits (measure-zero branch)
    for (int b = tid; b < HBUCKETS; b += 1024) H[b] = 0;
    __syncthreads();
    for (int l = 0; l < NLV; ++l)
      for (int t = tid; t < mcap[l]; t += 1024) {
        u64 key = mainG[(size_t)(img * NLV + l) * 1024 + t];
        u32 bits = (u32)(key >> 32);
        if (score_bucket(bits) == gx) atomicAdd(&H[(bits >> 6) & 1023], 1u);
      }
    __syncthreads();
    if (wid == 0) {
      int a1, a2;
      wave_find_cut(H, gy, lane, a1, a2);
      if (lane == 0) sh_sgx = a1;
    }
    __syncthreads();
    sgx = sh_sgx;
    if (sgx >= 0) {
      for (int s2 = tid; s2 < HBUCKETS; s2 += 1024)
        if (s2 >= sgx) { u32 v = H[s2]; if (v) atomicAdd(&sh_cand, (int)v); }
      __syncthreads();
      cand = sh_cand;
    }
    if (cA + cand > CAPSEL) cand = CAPSEL - cA;  // memory-safety clamp
  }
  __syncthreads();
  // scatter pass
  for (int l = 0; l < NLV; ++l)
    for (int t = tid; t < mcap[l]; t += 1024) {
      u64 key = mainG[(size_t)(img * NLV + l) * 1024 + t];
      u32 bits = (u32)(key >> 32);
      int b = score_bucket(bits);
      bool inc = false; int segbase = 0, seglen = 0;
      if (gx < 0 || b > gx) {
        inc = true; segbase = (int)(Sarr[b] - cntb[b]); seglen = (int)cntb[b];
      } else if (b == gx) {
        inc = (sgx < 0) || ((int)((bits >> 6) & 1023) >= sgx);
        segbase = (int)Sarr[b]; seglen = cand;
      }
      if (inc) {
        int slot = (int)atomicAdd(&cnt2[b], 1u);
        if (slot < seglen) sel[segbase + slot] = key;
      }
    }
  __syncthreads();
  int total = cA + cand;
  // exact in-bucket rank sort (in-place permutation; reads before writes)
  u64 myk[5]; int myp[5];
#pragma unroll
  for (int it = 0; it < 5; ++it) {
    int t = tid + it * 1024;
    myp[it] = -1; myk[it] = 0;
    if (t < total) {
      u64 key = sel[t];
      u32 bits = (u32)(key >> 32);
      int b = score_bucket(bits);
      int segbase, seglen;
      if (gx >= 0 && b == gx) { segbase = (int)Sarr[b]; seglen = cand; }
      else { segbase = (int)(Sarr[b] - cntb[b]); seglen = (int)cntb[b]; }
      int r = 0;
      for (int u = 0; u < seglen; ++u) r += (sel[segbase + u] > key) ? 1 : 0;
      myk[it] = key; myp[it] = segbase + r;
    }
  }
  __syncthreads();
#pragma unroll
  for (int it = 0; it < 5; ++it) if (myp[it] >= 0) sel[myp[it]] = myk[it];
  __syncthreads();
  // decode
  for (int t = tid; t < NPRE; t += 1024) {
    u64 key = (t < total) ? sel[t] : 0ULL;
    float4 bx = make_float4(0.f, 0.f, 0.f, 0.f);
    int c = -1;
    float sc = 0.f;
    if (key != 0ULL) {
      sc = __uint_as_float((u32)(key >> 32));
      u32 flat = 0xFFFFFFFFu - (u32)(key & 0xFFFFFFFFULL);
      int a = (int)(flat / NCLS);
      c = (int)(flat % NCLS);
      float4 p = priors[a];
      float4 r = reg[(size_t)img * A_TOTAL + a];
      float cx = p.x + (r.x * 0.1f) * p.z;
      float cy = p.y + (r.y * 0.1f) * p.w;
      float w = p.z * expf(r.z * 0.2f);
      float h = p.w * expf(r.w * 0.2f);
      bx.x = fminf(fmaxf(cx - w * 0.5f, 0.f), 512.f);
      bx.y = fminf(fmaxf(cy - h * 0.5f, 0.f), 512.f);
      bx.z = fminf(fmaxf(cx + w * 0.5f, 0.f), 512.f);
      bx.w = fminf(fmaxf(cy + h * 0.5f, 0.f), 512.f);
    }
    boxesG[(size_t)img * NPRE + t] = bx;
    clsG[(size_t)img * NPRE + t] = c;
    scoreG[(size_t)img * NPRE + t] = sc;
  }
}

// suppression bitmask: row i, bit j set iff j>i, same class, IoU>0.45
__global__ __launch_bounds__(256) void k_mask(const float4* __restrict__ boxesG,
                                              const int* __restrict__ clsG,
                                              u64* __restrict__ maskG) {
  __shared__ float4 lb[NPRE];
  __shared__ int lc[NPRE];
  int img = blockIdx.x / 500;
  int rb = (blockIdx.x % 500) * 4;
  for (int t = threadIdx.x; t < NPRE; t += 256) {
    lb[t] = boxesG[(size_t)img * NPRE + t];
    lc[t] = clsG[(size_t)img * NPRE + t];
  }
  __syncthreads();
  int w = threadIdx.x >> 6, lane = threadIdx.x & 63;
  int i = rb + w;
  float4 bi = lb[i];
  int ci = lc[i];
  float ai = (bi.z - bi.x) * (bi.w - bi.y);
  u64* mrow = maskG + ((size_t)img * NPRE + i) * 32;
  for (int ch = 0; ch < 32; ++ch) {
    int j = ch * 64 + lane;
    bool pred = false;
    if (j < NPRE && j > i) {
      if (lc[j] == ci) {
        float4 bj = lb[j];
        float xx1 = fmaxf(bi.x, bj.x), yy1 = fmaxf(bi.y, bj.y);
        float xx2 = fminf(bi.z, bj.z), yy2 = fminf(bi.w, bj.w);
        float ww = fmaxf(xx2 - xx1, 0.f), hh = fmaxf(yy2 - yy1, 0.f);
        float inter = ww * hh;
        float aj = (bj.z - bj.x) * (bj.w - bj.y);
        float iou = inter / fmaxf(ai + aj - inter, 1e-6f);
        pred = iou > 0.45f;
      }
    }
    u64 word = __ballot(pred);
    if (lane == 0) mrow[ch] = word;
  }
}

// greedy scan with early exit at 200 kept, fused with final gather.
__global__ __launch_bounds__(256) void k_scanfinal(const u64* __restrict__ maskG,
                                                   const float4* __restrict__ boxesG,
                                                   const int* __restrict__ clsG,
                                                   const float* __restrict__ scoreG,
                                                   float* __restrict__ out) {
  int img = blockIdx.x;
  int tid = threadIdx.x;
  __shared__ u64 sh_remv[32];
  __shared__ u32 keptList[216];
  __shared__ int sh_cnt, sh_done;
  __shared__ int kpref[257];
  __shared__ unsigned short S[NPRE];
  if (tid == 0) { sh_cnt = 0; sh_done = 0; }
  __syncthreads();
  if (tid < 64) {
    int lane = tid;
    int wl = lane & 31;
    const u64* M = maskG + (size_t)img * NPRE * 32;
    u64 remv = 0;
    u64 cur[16], nxt[16];
    int cnt = 0;
#pragma unroll
    for (int r = 0; r < 16; ++r) cur[r] = M[(size_t)r * 32 + wl];
    int t = 0;
    for (; t < 125; ++t) {
      if (t < 124) {
#pragma unroll
        for (int r = 0; r < 16; ++r) nxt[r] = M[(size_t)((t + 1) * 16 + r) * 32 + wl];
      }
#pragma unroll
      for (int r = 0; r < 16; ++r) {
        int i = t * 16 + r;
        u64 rm = shfl_u64(remv, i >> 6);
        if (!((rm >> (i & 63)) & 1ULL)) {
          remv |= cur[r];
          if (lane == 0 && cnt < 216) keptList[cnt] = (u32)i;
          ++cnt;
        }
      }
#pragma unroll
      for (int r = 0; r < 16; ++r) cur[r] = nxt[r];
      if (cnt >= 200) { ++t; break; }
    }
    if (lane == 0) sh_cnt = cnt < 216 ? cnt : 216;
    if (t >= 125) {
      if (lane == 0) sh_done = 1;
      if (lane < 32) sh_remv[lane] = remv;
    }
  }
  __syncthreads();
  int nK = sh_cnt;
  if (sh_done && nK < 200) {
    int base = tid * 8;
    bool sb[8];
    int scnt = 0;
#pragma unroll
    for (int e = 0; e < 8; ++e) {
      int i = base + e;
      bool sup = (i < NPRE) && ((sh_remv[i >> 6] >> (i & 63)) & 1ULL);
      sb[e] = sup;
      scnt += sup ? 1 : 0;
    }
    kpref[tid + 1] = scnt;
    if (tid == 0) kpref[0] = 0;
    __syncthreads();
    if (tid == 0) {
      int acc = 0;
      for (int t = 1; t <= 256; ++t) { acc += kpref[t]; kpref[t] = acc; }
    }
    __syncthreads();
    int sp = kpref[tid];
#pragma unroll
    for (int e = 0; e < 8; ++e) {
      int i = base + e;
      if (i < NPRE && sb[e]) S[sp++] = (unsigned short)i;
    }
    __syncthreads();
    if (tid < 200) {
      float fv = 0.f;
      float4 fb = make_float4(0.f, 0.f, 0.f, 0.f);
      int fc;
      if (tid < nK) {
        int idx = (int)keptList[tid];
        fv = scoreG[(size_t)img * NPRE + idx];
        fb = boxesG[(size_t)img * NPRE + idx];
        fc = clsG[(size_t)img * NPRE + idx];
      } else {
        int idx = S[tid - nK];
        fc = clsG[(size_t)img * NPRE + idx];
      }
      float* fbo = out + (size_t)img * 800 + tid * 4;
      fbo[0] = fb.x; fbo[1] = fb.y; fbo[2] = fb.z; fbo[3] = fb.w;
      out[3200 + (size_t)img * 200 + tid] = fv;
      out[4000 + (size_t)img * 200 + tid] = (float)fc;
    }
  } else {
    if (tid < 200) {
      int idx = (int)keptList[tid];
      float fv = scoreG[(size_t)img * NPRE + idx];
      float4 fb = boxesG[(size_t)img * NPRE + idx];
      int fc = clsG[(size_t)img * NPRE + idx];
      float* fbo = out + (size_t)img * 800 + tid * 4;
      fbo[0] = fb.x; fbo[1] = fb.y; fbo[2] = fb.z; fbo[3] = fb.w;
      out[3200 + (size_t)img * 200 + tid] = fv;
      out[4000 + (size_t)img * 200 + tid] = (float)fc;
    }
  }
}

extern "C" void kernel_launch(void* const* d_in, const int* in_sizes, int n_in,
                              void* d_out, int out_size, void* d_ws, size_t ws_size,
                              hipStream_t stream) {
  const float* logits = (const float*)d_in[0];
  const float4* reg = (const float4*)d_in[1];
  const float4* priors = (const float4*)d_in[2];
  char* ws = (char*)d_ws;
  u32* hist = (u32*)(ws + WS_HIST);
  u32* mcount = (u32*)(ws + WS_MCOUNT);
  u32* bcount = (u32*)(ws + WS_BCOUNT);
  u32* pcount = (u32*)(ws + WS_PCOUNT);
  int2* cuts = (int2*)(ws + WS_CUTS);
  u64* mainL = (u64*)(ws + WS_MAIN);
  u64* bndL = (u64*)(ws + WS_BND);
  float4* boxes = (float4*)(ws + WS_BOXES);
  int* cls = (int*)(ws + WS_CLS);
  float* score = (float*)(ws + WS_SCORE);
  u64* mask = (u64*)(ws + WS_MASK);
  u64* pool = (u64*)(ws + WS_POOL);

  size_t avail = ws_size > (size_t)WS_POOL ? ws_size - (size_t)WS_POOL : 0;
  int cap = (int)(avail / ((size_t)NBLK_F * 8));
  if (cap > POOL_CAP_MAX) cap = POOL_CAP_MAX;

  hipMemsetAsync(d_ws, 0, WS_ZERO_END, stream);
  k_fused<<<NBLK_F, FT, 0, stream>>>(logits, hist, pool, pcount, cap);
  k_cuts<<<1, 1024, 0, stream>>>(hist, cuts);
  k_filter<<<NBLK_F, FT, 0, stream>>>(logits, pool, pcount, cuts, cap,
                                      mainL, mcount, bndL, bcount);
  k_refine<<<28, 1024, 0, stream>>>(hist, bndL, bcount, mainL, mcount);
  k_gsel<<<NIMG, 1024, 0, stream>>>(hist, mainL, mcount, priors, reg, boxes, cls, score);
  k_mask<<<NIMG * 500, 256, 0, stream>>>(boxes, cls, mask);
  k_scanfinal<<<NIMG, 256, 0, stream>>>(mask, boxes, cls, score, (float*)d_out);
}

// Round 8
// 123.295 us; speedup vs baseline: 5.6263x; 1.0022x over previous
//
#include <hip/hip_runtime.h>
#include <hip/hip_bf16.h>
#include <math.h>

typedef unsigned long long u64;
typedef unsigned int u32;

#define A_TOTAL 24564
#define NCLS 80
#define NIMG 4
#define NPRE 2000
#define NLV 7
#define HBUCKETS 1024
#define BEXP_BASE 0x3CA3
#define TOTAL_G (NIMG * A_TOTAL)   // 98256
#define FA 64                      // anchors per block (fused/filter)
#define FT 256                     // threads per block
#define NBLK_F ((TOTAL_G + FA - 1) / FA)  // 1536
#define POOL_CAP_MAX 4096
#define CAPSEL 4608

__device__ __constant__ int c_klv[NLV] = {1000,1000,1000,1000,1000,1000,320};

// ---- workspace layout (bytes) ----
#define WS_HIST      0          // 28*1024*4 = 114688
#define WS_MCOUNT    114688     // 28*4
#define WS_BCOUNT    114800     // 28*4
#define WS_ZERO_END  114912     // hist+mcount+bcount only (pcount overwritten)
#define WS_PCOUNT    114912     // 1536*4 = 6144
#define WS_CUTS      121056     // 28*8 (overwritten every call)
#define WS_MAIN      121280     // 28*1024*8
#define WS_BND       350656     // 28*4096*8
#define WS_BOXES     1268160    // 4*2000*16
#define WS_CLS       1396160    // 4*2000*4
#define WS_SCORE     1428160    // 4*2000*4
#define WS_MASK      1460160    // 4*2000*32*8 = 2048000
#define WS_POOL      3508160    // NBLK_F * cap * 8, cap adaptive to ws_size

#define NZERO_W (WS_ZERO_END / 4)   // 28728 u32 words

__device__ inline u64 shfl_u64(u64 v, int src) {
  int lo = __shfl((int)(u32)(v & 0xFFFFFFFFULL), src);
  int hi = __shfl((int)(u32)(v >> 32), src);
  return ((u64)(u32)hi << 32) | (u32)lo;
}

__device__ inline int score_bucket(u32 bits) {
  int b = (int)(bits >> 16) - BEXP_BASE;
  return b < 0 ? 0 : (b > HBUCKETS - 1 ? HBUCKETS - 1 : b);
}

__device__ inline int level_of(int a) {
  return (a < 16384) ? 0 : (a < 22528) ? 1 : (a < 24064) ? 2 :
         (a < 24448) ? 3 : (a < 24544) ? 4 : (a < 24560) ? 5 : 6;
}

// replaces rocclr fillBufferAligned (was 41 us at 8% occupancy)
__global__ __launch_bounds__(256) void k_zero(u32* __restrict__ p) {
  int i = blockIdx.x * 256 + threadIdx.x;
  if (i < NZERO_W) p[i] = 0;
}

// One full wave finds (cut bucket, count-in-bucket) for top-k over a 1024-bin
// histogram h. Deterministic: same h,k -> same result.
__device__ inline void wave_find_cut(const u32* __restrict__ h, int k, int lane,
                                     int& cx, int& cy) {
  u32 s = 0;
#pragma unroll
  for (int i = 0; i < 16; ++i) s += h[lane * 16 + i];
  u32 S = s;  // inclusive suffix-sum across lanes
#pragma unroll
  for (int o = 1; o < 64; o <<= 1) {
    u32 t = (u32)__shfl_down((int)S, o);
    if (lane + o < 64) S += t;
  }
  u32 total = (u32)__shfl((int)S, 0);
  if (total <= (u32)k) { cx = -1; cy = 0; return; }
  u64 bm = __ballot(S >= (u32)k);
  int L0 = 63 - (int)__clzll((long long)bm);
  u32 Sup = (u32)__shfl_down((int)S, 1);
  if (lane == 63) Sup = 0;
  int rcx = 0, rcy = 0;
  if (lane == L0) {
    u32 cum = Sup;
    for (int i = 15; i >= 0; --i) {
      u32 c = h[lane * 16 + i];
      if (cum + c >= (u32)k) { rcx = lane * 16 + i; rcy = k - (int)cum; break; }
      cum += c;
    }
  }
  cx = __shfl(rcx, L0);
  cy = __shfl(rcy, L0);
}

// Single scoring pass: LDS-staged softmax (4 threads/anchor), per-seg score
// histogram, and emission of ALL above-threshold keys into this block's
// private pool slice. No global atomics; one LDS counter, batched.
__global__ __launch_bounds__(FT) void k_fused(const float* __restrict__ logits,
                                              u32* __restrict__ histG,
                                              u64* __restrict__ pool,
                                              u32* __restrict__ pcount, int cap) {
  __shared__ float sx[FA * 81];   // 20736 B
  __shared__ u32 sh[HBUCKETS];    // 4096 B
  __shared__ int nm;
  int tid = threadIdx.x, bx = blockIdx.x;
  for (int b = tid; b < HBUCKETS; b += FT) sh[b] = 0;
  if (tid == 0) nm = 0;
  size_t base_f = (size_t)bx * (FA * 81);
  int cap4 = FA * 81 / 4;
  long long rem4 = ((long long)TOTAL_G * 81 - (long long)base_f) / 4;
  int n4 = (rem4 > cap4) ? cap4 : (int)rem4;
  const float4* src = (const float4*)(logits + base_f);
  float4* dst = (float4*)sx;
  for (int t = tid; t < n4; t += FT) dst[t] = src[t];
  __syncthreads();
  int la = tid >> 2, q = tid & 3;
  int g = bx * FA + la;
  bool valid = g < TOTAL_G;
  int g0 = bx * FA;
  int seg0 = (g0 / A_TOTAL) * NLV + level_of(g0 % A_TOTAL);
  int seg = seg0, a = 0;
  float e[20];
  float rt = 0.f;
  if (valid) {
    int img = g / A_TOTAL;
    a = g - img * A_TOTAL;
    seg = img * NLV + level_of(a);
    int rowoff = la * 81, c0 = q * 20;
    float mloc = sx[rowoff + c0];
#pragma unroll
    for (int i = 1; i < 20; ++i) mloc = fmaxf(mloc, sx[rowoff + c0 + i]);
    if (q == 3) mloc = fmaxf(mloc, sx[rowoff + 80]);
    float m = fmaxf(mloc, __shfl_xor(mloc, 1));
    m = fmaxf(m, __shfl_xor(m, 2));
    float tq = 0.f;
#pragma unroll
    for (int i = 0; i < 20; ++i) { e[i] = expf(sx[rowoff + c0 + i] - m); tq += e[i]; }
    if (q == 3) tq += expf(sx[rowoff + 80] - m);
    float t = tq + __shfl_xor(tq, 1);
    t = t + __shfl_xor(t, 2);
    rt = 1.0f / t;
  }
  int uniform = __syncthreads_and((int)(!valid || seg == seg0));
  if (valid) {
    u32* hdst = uniform ? sh : (histG + (size_t)seg * HBUCKETS);
    int c0 = q * 20;
    u32 wmask = 0;
#pragma unroll
    for (int i = 0; i < 20; ++i) {
      float s = e[i] * rt;
      if (s > 0.02f) wmask |= (1u << i);
    }
    int cnt = __popc(wmask);
    int basep = 0;
    if (cnt) basep = atomicAdd(&nm, cnt);
    while (wmask) {
      int i = __ffs(wmask) - 1;
      wmask &= wmask - 1;
      float s = e[i] * rt;
      u32 bits = __float_as_uint(s);
      atomicAdd(&hdst[score_bucket(bits)], 1u);
      if (basep < cap)
        pool[(size_t)bx * cap + basep] =
            ((u64)bits << 32) | (u64)(0xFFFFFFFFu - (u32)(a * NCLS + c0 + i));
      ++basep;
    }
  }
  __syncthreads();
  if (uniform) {
    u32* hseg = histG + (size_t)seg0 * HBUCKETS;
    for (int b = tid; b < HBUCKETS; b += FT) {
      u32 v = sh[b];
      if (v) atomicAdd(&hseg[b], v);
    }
  }
  if (tid == 0) pcount[bx] = (u32)nm;
}

__global__ __launch_bounds__(1024) void k_cuts(const u32* __restrict__ histG,
                                               int2* __restrict__ cutsG) {
  int wid = threadIdx.x >> 6, lane = threadIdx.x & 63;
  for (int seg = wid; seg < NIMG * NLV; seg += 16) {
    int cx, cy;
    wave_find_cut(histG + (size_t)seg * HBUCKETS, c_klv[seg % NLV], lane, cx, cy);
    if (lane == 0) cutsG[seg] = make_int2(cx, cy);
  }
}

// Stream this block's pool slice, keep above-cut/boundary entries.
// Fallback (pool overflow, statistically never): recompute the block's
// anchors from logits with bit-identical arithmetic.
__global__ __launch_bounds__(FT) void k_filter(const float* __restrict__ logits,
                                               const u64* __restrict__ pool,
                                               const u32* __restrict__ pcount,
                                               const int2* __restrict__ cutsG, int cap,
                                               u64* __restrict__ mainG, u32* __restrict__ mcount,
                                               u64* __restrict__ bndG, u32* __restrict__ bcount) {
  __shared__ float sx[FA * 81];
  __shared__ int2 scuts[NIMG * NLV];
  __shared__ u64 mk[1024]; __shared__ unsigned char msg_[1024];
  __shared__ u64 bkl[256]; __shared__ unsigned char bsg[256];
  __shared__ int nm, nb, cm[4], cb[4], basem[4], baseb[4], wm[4], wb[4];
  int tid = threadIdx.x, bx = blockIdx.x;
  if (tid < NIMG * NLV) scuts[tid] = cutsG[tid];
  if (tid < 4) { cm[tid] = 0; cb[tid] = 0; wm[tid] = 0; wb[tid] = 0; }
  if (tid == 0) { nm = 0; nb = 0; }
  int g0 = bx * FA;
  int img0 = g0 / A_TOTAL;
  int alo = g0 - img0 * A_TOTAL;
  int gN = g0 + FA - 1; if (gN > TOTAL_G - 1) gN = TOTAL_G - 1;
  int seg_lo = img0 * NLV + level_of(alo);
  int seg_hi = (gN / A_TOTAL) * NLV + level_of(gN % A_TOTAL);
  __syncthreads();
  int n = (int)pcount[bx];
  if (n <= cap) {
    for (int t = tid; t < n; t += FT) {
      u64 key = pool[(size_t)bx * cap + t];
      u32 bits = (u32)(key >> 32);
      u32 flat = 0xFFFFFFFFu - (u32)(key & 0xFFFFFFFFULL);
      int a = (int)(flat / NCLS);
      int img = (a >= alo) ? img0 : img0 + 1;
      int seg = img * NLV + level_of(a);
      int2 ct = scuts[seg];
      int bk = score_bucket(bits);
      int si = seg - seg_lo;
      if (ct.x < 0 || bk > ct.x) {
        int p = atomicAdd(&nm, 1);
        if (p < 1024) { mk[p] = key; msg_[p] = (unsigned char)si; atomicAdd(&cm[si], 1); }
        else { u32 pg = atomicAdd(&mcount[seg], 1u); if (pg < 1024) mainG[(size_t)seg * 1024 + pg] = key; }
      } else if (bk == ct.x) {
        int p = atomicAdd(&nb, 1);
        if (p < 256) { bkl[p] = key; bsg[p] = (unsigned char)si; atomicAdd(&cb[si], 1); }
        else { u32 pg = atomicAdd(&bcount[seg], 1u); if (pg < 4096) bndG[(size_t)seg * 4096 + pg] = key; }
      }
    }
  } else {
    size_t base_f = (size_t)bx * (FA * 81);
    int cap4 = FA * 81 / 4;
    long long rem4 = ((long long)TOTAL_G * 81 - (long long)base_f) / 4;
    int n4 = (rem4 > cap4) ? cap4 : (int)rem4;
    const float4* src = (const float4*)(logits + base_f);
    float4* dst = (float4*)sx;
    for (int t = tid; t < n4; t += FT) dst[t] = src[t];
    __syncthreads();
    int la = tid >> 2, q = tid & 3;
    int g = g0 + la;
    if (g < TOTAL_G) {
      int img = g / A_TOTAL;
      int a = g - img * A_TOTAL;
      int seg = img * NLV + level_of(a);
      int si = seg - seg_lo;
      int2 ct = scuts[seg];
      int rowoff = la * 81, c0 = q * 20;
      float mloc = sx[rowoff + c0];
#pragma unroll
      for (int i = 1; i < 20; ++i) mloc = fmaxf(mloc, sx[rowoff + c0 + i]);
      if (q == 3) mloc = fmaxf(mloc, sx[rowoff + 80]);
      float m = fmaxf(mloc, __shfl_xor(mloc, 1));
      m = fmaxf(m, __shfl_xor(m, 2));
      float tq = 0.f;
      float e[20];
#pragma unroll
      for (int i = 0; i < 20; ++i) { e[i] = expf(sx[rowoff + c0 + i] - m); tq += e[i]; }
      if (q == 3) tq += expf(sx[rowoff + 80] - m);
      float tt = tq + __shfl_xor(tq, 1);
      tt = tt + __shfl_xor(tt, 2);
      float rt = 1.0f / tt;
      for (int i = 0; i < 20; ++i) {
        float s = e[i] * rt;
        if (s > 0.02f) {
          u32 bits = __float_as_uint(s);
          int bk = score_bucket(bits);
          u64 key = ((u64)bits << 32) | (u64)(0xFFFFFFFFu - (u32)(a * NCLS + c0 + i));
          if (ct.x < 0 || bk > ct.x) {
            int p = atomicAdd(&nm, 1);
            if (p < 1024) { mk[p] = key; msg_[p] = (unsigned char)si; atomicAdd(&cm[si], 1); }
            else { u32 pg = atomicAdd(&mcount[seg], 1u); if (pg < 1024) mainG[(size_t)seg * 1024 + pg] = key; }
          } else if (bk == ct.x) {
            int p = atomicAdd(&nb, 1);
            if (p < 256) { bkl[p] = key; bsg[p] = (unsigned char)si; atomicAdd(&cb[si], 1); }
            else { u32 pg = atomicAdd(&bcount[seg], 1u); if (pg < 4096) bndG[(size_t)seg * 4096 + pg] = key; }
          }
        }
      }
    }
  }
  __syncthreads();
  if (tid <= seg_hi - seg_lo) {
    if (cm[tid] > 0) basem[tid] = (int)atomicAdd(&mcount[seg_lo + tid], (u32)cm[tid]);
    if (cb[tid] > 0) baseb[tid] = (int)atomicAdd(&bcount[seg_lo + tid], (u32)cb[tid]);
  }
  __syncthreads();
  int tm = nm < 1024 ? nm : 1024;
  for (int idx = tid; idx < tm; idx += FT) {
    int si = msg_[idx];
    int slot = atomicAdd(&wm[si], 1);
    int d = basem[si] + slot;
    if (d < 1024) mainG[(size_t)(seg_lo + si) * 1024 + d] = mk[idx];
  }
  int tb = nb < 256 ? nb : 256;
  for (int idx = tid; idx < tb; idx += FT) {
    int si = bsg[idx];
    int slot = atomicAdd(&wb[si], 1);
    int d = baseb[si] + slot;
    if (d < 4096) bndG[(size_t)(seg_lo + si) * 4096 + d] = bkl[idx];
  }
}

__device__ inline void bitonic_desc(u64* s, int n) {
  for (int k = 2; k <= n; k <<= 1)
    for (int j = k >> 1; j > 0; j >>= 1) {
      __syncthreads();
      for (int i = threadIdx.x; i < n; i += blockDim.x) {
        int l = i ^ j;
        if (l > i) {
          u64 a = s[i], b = s[l];
          if (((i & k) == 0) ? (a < b) : (a > b)) { s[i] = b; s[l] = a; }
        }
      }
    }
  __syncthreads();
}

// exact per-level top-k: sort only pow2ceil(boundary count) elements
__global__ __launch_bounds__(1024) void k_refine(const u32* __restrict__ histG,
                                                 const u64* __restrict__ bndG,
                                                 const u32* __restrict__ bcount,
                                                 u64* __restrict__ mainG, u32* __restrict__ mcount) {
  int seg = blockIdx.x;
  __shared__ int sh_cx, sh_cy;
  __shared__ u64 s[4096];
  int tid = threadIdx.x, lane = tid & 63;
  if (tid < 64) {
    int cx, cy;
    wave_find_cut(histG + (size_t)seg * HBUCKETS, c_klv[seg % NLV], lane, cx, cy);
    if (lane == 0) { sh_cx = cx; sh_cy = cy; }
  }
  __syncthreads();
  if (sh_cx < 0) return;
  int m = (int)bcount[seg]; if (m > 4096) m = 4096;
  int n = 64; while (n < m) n <<= 1;
  for (int t = tid; t < n; t += 1024)
    s[t] = (t < m) ? bndG[(size_t)seg * 4096 + t] : 0ULL;
  bitonic_desc(s, n);
  int kp = sh_cy; if (kp > m) kp = m;
  int base = (int)mcount[seg];
  for (int t = tid; t < kp; t += 1024) {
    int p = base + t;
    if (p < 1024) mainG[(size_t)seg * 1024 + p] = s[t];
  }
  __syncthreads();
  if (tid == 0) {
    int nb = base + kp;
    mcount[seg] = (u32)(nb > 1024 ? 1024 : nb);
  }
}

// per-image: global cut from truncated per-level histograms, then histogram
// RANK-SORT (no bitonic): count per bucket -> suffix-scan bases -> scatter
// into bucket segments -> exact in-bucket rank by LDS scan -> permute in
// place. First NPRE positions = exact sorted top-2000. Decode inline.
__global__ __launch_bounds__(1024) void k_gsel(const u32* __restrict__ histG,
                                               const u64* __restrict__ mainG,
                                               const u32* __restrict__ mcount,
                                               const float4* __restrict__ priors,
                                               const float4* __restrict__ reg,
                                               float4* __restrict__ boxesG,
                                               int* __restrict__ clsG,
                                               float* __restrict__ scoreG) {
  int img = blockIdx.x;
  int tid = threadIdx.x, wid = tid >> 6, lane = tid & 63;
  __shared__ u32 H[HBUCKETS];     // merged hist; then scan pong; then subhist
  __shared__ u32 cntb[HBUCKETS];
  __shared__ u32 Sarr[HBUCKETS];  // inclusive suffix sums
  __shared__ u32 cnt2[HBUCKETS];
  __shared__ u64 sel[CAPSEL];     // 36864 B
  __shared__ int lcx[NLV], lcy[NLV];
  __shared__ int sh_gx, sh_gy, sh_cC, sh_cand, sh_sgx;
  if (tid == 0) { sh_cC = 0; sh_cand = 0; sh_sgx = -1; }
  if (wid < NLV) {
    int cx, cy;
    wave_find_cut(histG + (size_t)(img * NLV + wid) * HBUCKETS, c_klv[wid], lane, cx, cy);
    if (lane == 0) { lcx[wid] = cx; lcy[wid] = cy; }
  }
  __syncthreads();
  for (int b = tid; b < HBUCKETS; b += 1024) {
    u32 acc = 0;
#pragma unroll
    for (int l = 0; l < NLV; ++l) {
      u32 h = histG[(size_t)(img * NLV + l) * HBUCKETS + b];
      int cx = lcx[l];
      if (cx < 0 || b > cx) acc += h;
      else if (b == cx) acc += (u32)lcy[l];
    }
    H[b] = acc;
    cntb[b] = 0;
    cnt2[b] = 0;
  }
  __syncthreads();
  if (wid == 0) {
    int gx, gy;
    wave_find_cut(H, NPRE, lane, gx, gy);
    if (lane == 0) { sh_gx = gx; sh_gy = gy; }
  }
  __syncthreads();
  int gx = sh_gx, gy = sh_gy;
  int mcap[NLV];
#pragma unroll
  for (int l = 0; l < NLV; ++l) { int c = (int)mcount[img * NLV + l]; mcap[l] = c > 1024 ? 1024 : c; }
  // count pass
  for (int l = 0; l < NLV; ++l)
    for (int t = tid; t < mcap[l]; t += 1024) {
      u64 key = mainG[(size_t)(img * NLV + l) * 1024 + t];
      int b = score_bucket((u32)(key >> 32));
      if (gx < 0 || b > gx) atomicAdd(&cntb[b], 1u);
      else if (b == gx) atomicAdd(&sh_cC, 1);
    }
  __syncthreads();
  // inclusive suffix scan cntb -> Sarr (ping-pong with H; 10 steps -> Sarr)
  for (int b = tid; b < HBUCKETS; b += 1024) Sarr[b] = cntb[b];
  __syncthreads();
  {
    u32* A = Sarr; u32* B = H;
    for (int o = 1; o < HBUCKETS; o <<= 1) {
      for (int b = tid; b < HBUCKETS; b += 1024)
        B[b] = A[b] + ((b + o < HBUCKETS) ? A[b + o] : 0u);
      __syncthreads();
      u32* tmp = A; A = B; B = tmp;
    }
  }
  int cA = (int)Sarr[0];
  int cC = sh_cC;
  int cand = (gx >= 0) ? cC : 0;
  int sgx = -1;
  if (gx >= 0 && cA + cC > CAPSEL) {
    // sub-refine cut bucket by next 10 mantissa bits (measure-zero branch)
    for (int b = tid; b < HBUCKETS; b += 1024) H[b] = 0;
    __syncthreads();
    for (int l = 0; l < NLV; ++l)
      for (int t = tid; t < mcap[l]; t += 1024) {
        u64 key = mainG[(size_t)(img * NLV + l) * 1024 + t];
        u32 bits = (u32)(key >> 32);
        if (score_bucket(bits) == gx) atomicAdd(&H[(bits >> 6) & 1023], 1u);
      }
    __syncthreads();
    if (wid == 0) {
      int a1, a2;
      wave_find_cut(H, gy, lane, a1, a2);
      if (lane == 0) sh_sgx = a1;
    }
    __syncthreads();
    sgx = sh_sgx;
    if (sgx >= 0) {
      for (int s2 = tid; s2 < HBUCKETS; s2 += 1024)
        if (s2 >= sgx) { u32 v = H[s2]; if (v) atomicAdd(&sh_cand, (int)v); }
      __syncthreads();
      cand = sh_cand;
    }
    if (cA + cand > CAPSEL) cand = CAPSEL - cA;  // memory-safety clamp
  }
  __syncthreads();
  // scatter pass
  for (int l = 0; l < NLV; ++l)
    for (int t = tid; t < mcap[l]; t += 1024) {
      u64 key = mainG[(size_t)(img * NLV + l) * 1024 + t];
      u32 bits = (u32)(key >> 32);
      int b = score_bucket(bits);
      bool inc = false; int segbase = 0, seglen = 0;
      if (gx < 0 || b > gx) {
        inc = true; segbase = (int)(Sarr[b] - cntb[b]); seglen = (int)cntb[b];
      } else if (b == gx) {
        inc = (sgx < 0) || ((int)((bits >> 6) & 1023) >= sgx);
        segbase = (int)Sarr[b]; seglen = cand;
      }
      if (inc) {
        int slot = (int)atomicAdd(&cnt2[b], 1u);
        if (slot < seglen) sel[segbase + slot] = key;
      }
    }
  __syncthreads();
  int total = cA + cand;
  // exact in-bucket rank sort (in-place permutation; reads before writes)
  u64 myk[5]; int myp[5];
#pragma unroll
  for (int it = 0; it < 5; ++it) {
    int t = tid + it * 1024;
    myp[it] = -1; myk[it] = 0;
    if (t < total) {
      u64 key = sel[t];
      u32 bits = (u32)(key >> 32);
      int b = score_bucket(bits);
      int segbase, seglen;
      if (gx >= 0 && b == gx) { segbase = (int)Sarr[b]; seglen = cand; }
      else { segbase = (int)(Sarr[b] - cntb[b]); seglen = (int)cntb[b]; }
      int r = 0;
      for (int u = 0; u < seglen; ++u) r += (sel[segbase + u] > key) ? 1 : 0;
      myk[it] = key; myp[it] = segbase + r;
    }
  }
  __syncthreads();
#pragma unroll
  for (int it = 0; it < 5; ++it) if (myp[it] >= 0) sel[myp[it]] = myk[it];
  __syncthreads();
  // decode
  for (int t = tid; t < NPRE; t += 1024) {
    u64 key = (t < total) ? sel[t] : 0ULL;
    float4 bx = make_float4(0.f, 0.f, 0.f, 0.f);
    int c = -1;
    float sc = 0.f;
    if (key != 0ULL) {
      sc = __uint_as_float((u32)(key >> 32));
      u32 flat = 0xFFFFFFFFu - (u32)(key & 0xFFFFFFFFULL);
      int a = (int)(flat / NCLS);
      c = (int)(flat % NCLS);
      float4 p = priors[a];
      float4 r = reg[(size_t)img * A_TOTAL + a];
      float cx = p.x + (r.x * 0.1f) * p.z;
      float cy = p.y + (r.y * 0.1f) * p.w;
      float w = p.z * expf(r.z * 0.2f);
      float h = p.w * expf(r.w * 0.2f);
      bx.x = fminf(fmaxf(cx - w * 0.5f, 0.f), 512.f);
      bx.y = fminf(fmaxf(cy - h * 0.5f, 0.f), 512.f);
      bx.z = fminf(fmaxf(cx + w * 0.5f, 0.f), 512.f);
      bx.w = fminf(fmaxf(cy + h * 0.5f, 0.f), 512.f);
    }
    boxesG[(size_t)img * NPRE + t] = bx;
    clsG[(size_t)img * NPRE + t] = c;
    scoreG[(size_t)img * NPRE + t] = sc;
  }
}

// suppression bitmask: row i, bit j set iff j>i, same class, IoU>0.45
__global__ __launch_bounds__(256) void k_mask(const float4* __restrict__ boxesG,
                                              const int* __restrict__ clsG,
                                              u64* __restrict__ maskG) {
  __shared__ float4 lb[NPRE];
  __shared__ int lc[NPRE];
  int img = blockIdx.x / 500;
  int rb = (blockIdx.x % 500) * 4;
  for (int t = threadIdx.x; t < NPRE; t += 256) {
    lb[t] = boxesG[(size_t)img * NPRE + t];
    lc[t] = clsG[(size_t)img * NPRE + t];
  }
  __syncthreads();
  int w = threadIdx.x >> 6, lane = threadIdx.x & 63;
  int i = rb + w;
  float4 bi = lb[i];
  int ci = lc[i];
  float ai = (bi.z - bi.x) * (bi.w - bi.y);
  u64* mrow = maskG + ((size_t)img * NPRE + i) * 32;
  for (int ch = 0; ch < 32; ++ch) {
    int j = ch * 64 + lane;
    bool pred = false;
    if (j < NPRE && j > i) {
      if (lc[j] == ci) {
        float4 bj = lb[j];
        float xx1 = fmaxf(bi.x, bj.x), yy1 = fmaxf(bi.y, bj.y);
        float xx2 = fminf(bi.z, bj.z), yy2 = fminf(bi.w, bj.w);
        float ww = fmaxf(xx2 - xx1, 0.f), hh = fmaxf(yy2 - yy1, 0.f);
        float inter = ww * hh;
        float aj = (bj.z - bj.x) * (bj.w - bj.y);
        float iou = inter / fmaxf(ai + aj - inter, 1e-6f);
        pred = iou > 0.45f;
      }
    }
    u64 word = __ballot(pred);
    if (lane == 0) mrow[ch] = word;
  }
}

// greedy scan with early exit at 200 kept, fused with final gather.
__global__ __launch_bounds__(256) void k_scanfinal(const u64* __restrict__ maskG,
                                                   const float4* __restrict__ boxesG,
                                                   const int* __restrict__ clsG,
                                                   const float* __restrict__ scoreG,
                                                   float* __restrict__ out) {
  int img = blockIdx.x;
  int tid = threadIdx.x;
  __shared__ u64 sh_remv[32];
  __shared__ u32 keptList[216];
  __shared__ int sh_cnt, sh_done;
  __shared__ int kpref[257];
  __shared__ unsigned short S[NPRE];
  if (tid == 0) { sh_cnt = 0; sh_done = 0; }
  __syncthreads();
  if (tid < 64) {
    int lane = tid;
    int wl = lane & 31;
    const u64* M = maskG + (size_t)img * NPRE * 32;
    u64 remv = 0;
    u64 cur[16], nxt[16];
    int cnt = 0;
#pragma unroll
    for (int r = 0; r < 16; ++r) cur[r] = M[(size_t)r * 32 + wl];
    int t = 0;
    for (; t < 125; ++t) {
      if (t < 124) {
#pragma unroll
        for (int r = 0; r < 16; ++r) nxt[r] = M[(size_t)((t + 1) * 16 + r) * 32 + wl];
      }
#pragma unroll
      for (int r = 0; r < 16; ++r) {
        int i = t * 16 + r;
        u64 rm = shfl_u64(remv, i >> 6);
        if (!((rm >> (i & 63)) & 1ULL)) {
          remv |= cur[r];
          if (lane == 0 && cnt < 216) keptList[cnt] = (u32)i;
          ++cnt;
        }
      }
#pragma unroll
      for (int r = 0; r < 16; ++r) cur[r] = nxt[r];
      if (cnt >= 200) { ++t; break; }
    }
    if (lane == 0) sh_cnt = cnt < 216 ? cnt : 216;
    if (t >= 125) {
      if (lane == 0) sh_done = 1;
      if (lane < 32) sh_remv[lane] = remv;
    }
  }
  __syncthreads();
  int nK = sh_cnt;
  if (sh_done && nK < 200) {
    int base = tid * 8;
    bool sb[8];
    int scnt = 0;
#pragma unroll
    for (int e = 0; e < 8; ++e) {
      int i = base + e;
      bool sup = (i < NPRE) && ((sh_remv[i >> 6] >> (i & 63)) & 1ULL);
      sb[e] = sup;
      scnt += sup ? 1 : 0;
    }
    kpref[tid + 1] = scnt;
    if (tid == 0) kpref[0] = 0;
    __syncthreads();
    if (tid == 0) {
      int acc = 0;
      for (int t = 1; t <= 256; ++t) { acc += kpref[t]; kpref[t] = acc; }
    }
    __syncthreads();
    int sp = kpref[tid];
#pragma unroll
    for (int e = 0; e < 8; ++e) {
      int i = base + e;
      if (i < NPRE && sb[e]) S[sp++] = (unsigned short)i;
    }
    __syncthreads();
    if (tid < 200) {
      float fv = 0.f;
      float4 fb = make_float4(0.f, 0.f, 0.f, 0.f);
      int fc;
      if (tid < nK) {
        int idx = (int)keptList[tid];
        fv = scoreG[(size_t)img * NPRE + idx];
        fb = boxesG[(size_t)img * NPRE + idx];
        fc = clsG[(size_t)img * NPRE + idx];
      } else {
        int idx = S[tid - nK];
        fc = clsG[(size_t)img * NPRE + idx];
      }
      float* fbo = out + (size_t)img * 800 + tid * 4;
      fbo[0] = fb.x; fbo[1] = fb.y; fbo[2] = fb.z; fbo[3] = fb.w;
      out[3200 + (size_t)img * 200 + tid] = fv;
      out[4000 + (size_t)img * 200 + tid] = (float)fc;
    }
  } else {
    if (tid < 200) {
      int idx = (int)keptList[tid];
      float fv = scoreG[(size_t)img * NPRE + idx];
      float4 fb = boxesG[(size_t)img * NPRE + idx];
      int fc = clsG[(size_t)img * NPRE + idx];
      float* fbo = out + (size_t)img * 800 + tid * 4;
      fbo[0] = fb.x; fbo[1] = fb.y; fbo[2] = fb.z; fbo[3] = fb.w;
      out[3200 + (size_t)img * 200 + tid] = fv;
      out[4000 + (size_t)img * 200 + tid] = (float)fc;
    }
  }
}

extern "C" void kernel_launch(void* const* d_in, const int* in_sizes, int n_in,
                              void* d_out, int out_size, void* d_ws, size_t ws_size,
                              hipStream_t stream) {
  const float* logits = (const float*)d_in[0];
  const float4* reg = (const float4*)d_in[1];
  const float4* priors = (const float4*)d_in[2];
  char* ws = (char*)d_ws;
  u32* hist = (u32*)(ws + WS_HIST);
  u32* mcount = (u32*)(ws + WS_MCOUNT);
  u32* bcount = (u32*)(ws + WS_BCOUNT);
  u32* pcount = (u32*)(ws + WS_PCOUNT);
  int2* cuts = (int2*)(ws + WS_CUTS);
  u64* mainL = (u64*)(ws + WS_MAIN);
  u64* bndL = (u64*)(ws + WS_BND);
  float4* boxes = (float4*)(ws + WS_BOXES);
  int* cls = (int*)(ws + WS_CLS);
  float* score = (float*)(ws + WS_SCORE);
  u64* mask = (u64*)(ws + WS_MASK);
  u64* pool = (u64*)(ws + WS_POOL);

  size_t avail = ws_size > (size_t)WS_POOL ? ws_size - (size_t)WS_POOL : 0;
  int cap = (int)(avail / ((size_t)NBLK_F * 8));
  if (cap > POOL_CAP_MAX) cap = POOL_CAP_MAX;

  k_zero<<<(NZERO_W + 255) / 256, 256, 0, stream>>>((u32*)d_ws);
  k_fused<<<NBLK_F, FT, 0, stream>>>(logits, hist, pool, pcount, cap);
  k_cuts<<<1, 1024, 0, stream>>>(hist, cuts);
  k_filter<<<NBLK_F, FT, 0, stream>>>(logits, pool, pcount, cuts, cap,
                                      mainL, mcount, bndL, bcount);
  k_refine<<<28, 1024, 0, stream>>>(hist, bndL, bcount, mainL, mcount);
  k_gsel<<<NIMG, 1024, 0, stream>>>(hist, mainL, mcount, priors, reg, boxes, cls, score);
  k_mask<<<NIMG * 500, 256, 0, stream>>>(boxes, cls, mask);
  k_scanfinal<<<NIMG, 256, 0, stream>>>(mask, boxes, cls, score, (float*)d_out);
}

// Round 9
// 113.544 us; speedup vs baseline: 6.1094x; 1.0859x over previous
//
#include <hip/hip_runtime.h>
#include <hip/hip_bf16.h>
#include <math.h>

typedef unsigned long long u64;
typedef unsigned int u32;

#define A_TOTAL 24564
#define NCLS 80
#define NIMG 4
#define NPRE 2000
#define NLV 7
#define HBUCKETS 1024
#define BEXP_BASE 0x3CA3
#define TOTAL_G (NIMG * A_TOTAL)   // 98256
#define FA 64                      // anchors per block (fused/filter)
#define FT 256                     // threads per block (4 per anchor)
#define NBLK_F ((TOTAL_G + FA - 1) / FA)  // 1536
#define POOL_CAP_MAX 4096
#define CAPSEL 4608

__device__ __constant__ int c_klv[NLV] = {1000,1000,1000,1000,1000,1000,320};

// ---- workspace layout (bytes) ----
#define WS_HIST      0          // 28*1024*4 = 114688
#define WS_MCOUNT    114688     // 28*4
#define WS_BCOUNT    114800     // 28*4
#define WS_ZERO_END  114912     // hist+mcount+bcount only (pcount overwritten)
#define WS_PCOUNT    114912     // 1536*4 = 6144
#define WS_MAIN      121280     // 28*1024*8
#define WS_BND       350656     // 28*4096*8
#define WS_BOXES     1268160    // 4*2000*16
#define WS_CLS       1396160    // 4*2000*4
#define WS_SCORE     1428160    // 4*2000*4
#define WS_MASK      1460160    // 4*2000*32*8 = 2048000
#define WS_POOL      3508160    // NBLK_F * cap * 8, cap adaptive to ws_size

#define NZERO_W (WS_ZERO_END / 4)   // 28728 u32 words

__device__ inline u64 shfl_u64(u64 v, int src) {
  int lo = __shfl((int)(u32)(v & 0xFFFFFFFFULL), src);
  int hi = __shfl((int)(u32)(v >> 32), src);
  return ((u64)(u32)hi << 32) | (u32)lo;
}

__device__ inline int score_bucket(u32 bits) {
  int b = (int)(bits >> 16) - BEXP_BASE;
  return b < 0 ? 0 : (b > HBUCKETS - 1 ? HBUCKETS - 1 : b);
}

__device__ inline int level_of(int a) {
  return (a < 16384) ? 0 : (a < 22528) ? 1 : (a < 24064) ? 2 :
         (a < 24448) ? 3 : (a < 24544) ? 4 : (a < 24560) ? 5 : 6;
}

// replaces rocclr fillBufferAligned for our small zero region
__global__ __launch_bounds__(256) void k_zero(u32* __restrict__ p) {
  int i = blockIdx.x * 256 + threadIdx.x;
  if (i < NZERO_W) p[i] = 0;
}

// Registers-only softmax for one anchor, 4 threads/anchor (quad q=0..3 owns
// classes [20q,20q+20); q==3 also folds class 80 into max/sum). Direct
// scalar global loads (rows are 324 B, only 4-B aligned). SINGLE source of
// truth so k_filter's fallback reproduces identical bits.
__device__ inline void score20(const float* __restrict__ logits, int g, int q,
                               float (&e)[20], float& rt) {
  const float* row = logits + (size_t)g * 81;
  float x[20];
#pragma unroll
  for (int i = 0; i < 20; ++i) x[i] = row[q * 20 + i];
  float x80 = (q == 3) ? row[80] : 0.f;
  float mloc = x[0];
#pragma unroll
  for (int i = 1; i < 20; ++i) mloc = fmaxf(mloc, x[i]);
  if (q == 3) mloc = fmaxf(mloc, x80);
  float m = fmaxf(mloc, __shfl_xor(mloc, 1));
  m = fmaxf(m, __shfl_xor(m, 2));
  float tq = 0.f;
#pragma unroll
  for (int i = 0; i < 20; ++i) { e[i] = expf(x[i] - m); tq += e[i]; }
  if (q == 3) tq += expf(x80 - m);
  float t = tq + __shfl_xor(tq, 1);
  t = t + __shfl_xor(t, 2);
  rt = 1.0f / t;
}

// One full wave finds (cut bucket, count-in-bucket) for top-k over a 1024-bin
// histogram h. Deterministic: same h,k -> same result.
__device__ inline void wave_find_cut(const u32* __restrict__ h, int k, int lane,
                                     int& cx, int& cy) {
  u32 s = 0;
#pragma unroll
  for (int i = 0; i < 16; ++i) s += h[lane * 16 + i];
  u32 S = s;  // inclusive suffix-sum across lanes
#pragma unroll
  for (int o = 1; o < 64; o <<= 1) {
    u32 t = (u32)__shfl_down((int)S, o);
    if (lane + o < 64) S += t;
  }
  u32 total = (u32)__shfl((int)S, 0);
  if (total <= (u32)k) { cx = -1; cy = 0; return; }
  u64 bm = __ballot(S >= (u32)k);
  int L0 = 63 - (int)__clzll((long long)bm);
  u32 Sup = (u32)__shfl_down((int)S, 1);
  if (lane == 63) Sup = 0;
  int rcx = 0, rcy = 0;
  if (lane == L0) {
    u32 cum = Sup;
    for (int i = 15; i >= 0; --i) {
      u32 c = h[lane * 16 + i];
      if (cum + c >= (u32)k) { rcx = lane * 16 + i; rcy = k - (int)cum; break; }
      cum += c;
    }
  }
  cx = __shfl(rcx, L0);
  cy = __shfl(rcy, L0);
}

// Single scoring pass: registers-only softmax, per-seg score histogram,
// emission of ALL above-threshold keys into this block's pool slice.
__global__ __launch_bounds__(FT) void k_fused(const float* __restrict__ logits,
                                              u32* __restrict__ histG,
                                              u64* __restrict__ pool,
                                              u32* __restrict__ pcount, int cap) {
  __shared__ u32 sh[HBUCKETS];    // 4096 B
  __shared__ int nm;
  int tid = threadIdx.x, bx = blockIdx.x;
  for (int b = tid; b < HBUCKETS; b += FT) sh[b] = 0;
  if (tid == 0) nm = 0;
  int la = tid >> 2, q = tid & 3;
  int g = bx * FA + la;
  bool valid = g < TOTAL_G;
  int g0 = bx * FA;
  int seg0 = (g0 / A_TOTAL) * NLV + level_of(g0 % A_TOTAL);
  int seg = seg0, a = 0;
  float e[20];
  float rt = 0.f;
  if (valid) {
    int img = g / A_TOTAL;
    a = g - img * A_TOTAL;
    seg = img * NLV + level_of(a);
    score20(logits, g, q, e, rt);
  }
  int uniform = __syncthreads_and((int)(!valid || seg == seg0));
  if (valid) {
    u32* hdst = uniform ? sh : (histG + (size_t)seg * HBUCKETS);
    int c0 = q * 20;
    u32 wmask = 0;
#pragma unroll
    for (int i = 0; i < 20; ++i) {
      float s = e[i] * rt;
      if (s > 0.02f) wmask |= (1u << i);
    }
    int cnt = __popc(wmask);
    int basep = 0;
    if (cnt) basep = atomicAdd(&nm, cnt);
    while (wmask) {
      int i = __ffs(wmask) - 1;
      wmask &= wmask - 1;
      float s = e[i] * rt;
      u32 bits = __float_as_uint(s);
      atomicAdd(&hdst[score_bucket(bits)], 1u);
      if (basep < cap)
        pool[(size_t)bx * cap + basep] =
            ((u64)bits << 32) | (u64)(0xFFFFFFFFu - (u32)(a * NCLS + c0 + i));
      ++basep;
    }
  }
  __syncthreads();
  if (uniform) {
    u32* hseg = histG + (size_t)seg0 * HBUCKETS;
    for (int b = tid; b < HBUCKETS; b += FT) {
      u32 v = sh[b];
      if (v) atomicAdd(&hseg[b], v);
    }
  }
  if (tid == 0) pcount[bx] = (u32)nm;
}

// Stream this block's pool slice; per-block cut re-derivation (<=4 segs,
// deterministic from histG). Fallback (pool overflow, statistically never):
// registers-only recompute via score20 -> identical bits.
__global__ __launch_bounds__(FT) void k_filter(const float* __restrict__ logits,
                                               const u64* __restrict__ pool,
                                               const u32* __restrict__ pcount,
                                               const u32* __restrict__ histG, int cap,
                                               u64* __restrict__ mainG, u32* __restrict__ mcount,
                                               u64* __restrict__ bndG, u32* __restrict__ bcount) {
  __shared__ int lcx4[4];
  __shared__ u64 mk[1024]; __shared__ unsigned char msg_[1024];
  __shared__ u64 bkl[256]; __shared__ unsigned char bsg[256];
  __shared__ int nm, nb, cm[4], cb[4], basem[4], baseb[4], wm[4], wb[4];
  int tid = threadIdx.x, bx = blockIdx.x;
  if (tid < 4) { cm[tid] = 0; cb[tid] = 0; wm[tid] = 0; wb[tid] = 0; }
  if (tid == 0) { nm = 0; nb = 0; }
  int g0 = bx * FA;
  int img0 = g0 / A_TOTAL;
  int alo = g0 - img0 * A_TOTAL;
  int gN = g0 + FA - 1; if (gN > TOTAL_G - 1) gN = TOTAL_G - 1;
  int seg_lo = img0 * NLV + level_of(alo);
  int seg_hi = (gN / A_TOTAL) * NLV + level_of(gN % A_TOTAL);
  int nseg = seg_hi - seg_lo + 1;   // <= 4 by construction
  int wid = tid >> 6, lane = tid & 63;
  if (wid < nseg) {
    int cx, cy;
    wave_find_cut(histG + (size_t)(seg_lo + wid) * HBUCKETS,
                  c_klv[(seg_lo + wid) % NLV], lane, cx, cy);
    if (lane == 0) lcx4[wid] = cx;
  }
  __syncthreads();
  int n = (int)pcount[bx];
  if (n <= cap) {
    for (int t = tid; t < n; t += FT) {
      u64 key = pool[(size_t)bx * cap + t];
      u32 bits = (u32)(key >> 32);
      u32 flat = 0xFFFFFFFFu - (u32)(key & 0xFFFFFFFFULL);
      int a = (int)(flat / NCLS);
      int img = (a >= alo) ? img0 : img0 + 1;
      int seg = img * NLV + level_of(a);
      int si = seg - seg_lo;
      int ctx = lcx4[si];
      int bk = score_bucket(bits);
      if (ctx < 0 || bk > ctx) {
        int p = atomicAdd(&nm, 1);
        if (p < 1024) { mk[p] = key; msg_[p] = (unsigned char)si; atomicAdd(&cm[si], 1); }
        else { u32 pg = atomicAdd(&mcount[seg], 1u); if (pg < 1024) mainG[(size_t)seg * 1024 + pg] = key; }
      } else if (bk == ctx) {
        int p = atomicAdd(&nb, 1);
        if (p < 256) { bkl[p] = key; bsg[p] = (unsigned char)si; atomicAdd(&cb[si], 1); }
        else { u32 pg = atomicAdd(&bcount[seg], 1u); if (pg < 4096) bndG[(size_t)seg * 4096 + pg] = key; }
      }
    }
  } else {
    int la = tid >> 2, q = tid & 3;
    int g = g0 + la;
    if (g < TOTAL_G) {
      int img = g / A_TOTAL;
      int a = g - img * A_TOTAL;
      int seg = img * NLV + level_of(a);
      int si = seg - seg_lo;
      int ctx = lcx4[si];
      float e[20];
      float rt;
      score20(logits, g, q, e, rt);
      int c0 = q * 20;
      for (int i = 0; i < 20; ++i) {
        float s = e[i] * rt;
        if (s > 0.02f) {
          u32 bits = __float_as_uint(s);
          int bk = score_bucket(bits);
          u64 key = ((u64)bits << 32) | (u64)(0xFFFFFFFFu - (u32)(a * NCLS + c0 + i));
          if (ctx < 0 || bk > ctx) {
            int p = atomicAdd(&nm, 1);
            if (p < 1024) { mk[p] = key; msg_[p] = (unsigned char)si; atomicAdd(&cm[si], 1); }
            else { u32 pg = atomicAdd(&mcount[seg], 1u); if (pg < 1024) mainG[(size_t)seg * 1024 + pg] = key; }
          } else if (bk == ctx) {
            int p = atomicAdd(&nb, 1);
            if (p < 256) { bkl[p] = key; bsg[p] = (unsigned char)si; atomicAdd(&cb[si], 1); }
            else { u32 pg = atomicAdd(&bcount[seg], 1u); if (pg < 4096) bndG[(size_t)seg * 4096 + pg] = key; }
          }
        }
      }
    }
  }
  __syncthreads();
  if (tid < nseg) {
    if (cm[tid] > 0) basem[tid] = (int)atomicAdd(&mcount[seg_lo + tid], (u32)cm[tid]);
    if (cb[tid] > 0) baseb[tid] = (int)atomicAdd(&bcount[seg_lo + tid], (u32)cb[tid]);
  }
  __syncthreads();
  int tm = nm < 1024 ? nm : 1024;
  for (int idx = tid; idx < tm; idx += FT) {
    int si = msg_[idx];
    int slot = atomicAdd(&wm[si], 1);
    int d = basem[si] + slot;
    if (d < 1024) mainG[(size_t)(seg_lo + si) * 1024 + d] = mk[idx];
  }
  int tb = nb < 256 ? nb : 256;
  for (int idx = tid; idx < tb; idx += FT) {
    int si = bsg[idx];
    int slot = atomicAdd(&wb[si], 1);
    int d = baseb[si] + slot;
    if (d < 4096) bndG[(size_t)(seg_lo + si) * 4096 + d] = bkl[idx];
  }
}

__device__ inline void bitonic_desc(u64* s, int n) {
  for (int k = 2; k <= n; k <<= 1)
    for (int j = k >> 1; j > 0; j >>= 1) {
      __syncthreads();
      for (int i = threadIdx.x; i < n; i += blockDim.x) {
        int l = i ^ j;
        if (l > i) {
          u64 a = s[i], b = s[l];
          if (((i & k) == 0) ? (a < b) : (a > b)) { s[i] = b; s[l] = a; }
        }
      }
    }
  __syncthreads();
}

// exact per-level top-k: sort only pow2ceil(boundary count) elements
__global__ __launch_bounds__(1024) void k_refine(const u32* __restrict__ histG,
                                                 const u64* __restrict__ bndG,
                                                 const u32* __restrict__ bcount,
                                                 u64* __restrict__ mainG, u32* __restrict__ mcount) {
  int seg = blockIdx.x;
  __shared__ int sh_cx, sh_cy;
  __shared__ u64 s[4096];
  int tid = threadIdx.x, lane = tid & 63;
  if (tid < 64) {
    int cx, cy;
    wave_find_cut(histG + (size_t)seg * HBUCKETS, c_klv[seg % NLV], lane, cx, cy);
    if (lane == 0) { sh_cx = cx; sh_cy = cy; }
  }
  __syncthreads();
  if (sh_cx < 0) return;
  int m = (int)bcount[seg]; if (m > 4096) m = 4096;
  int n = 64; while (n < m) n <<= 1;
  for (int t = tid; t < n; t += 1024)
    s[t] = (t < m) ? bndG[(size_t)seg * 4096 + t] : 0ULL;
  bitonic_desc(s, n);
  int kp = sh_cy; if (kp > m) kp = m;
  int base = (int)mcount[seg];
  for (int t = tid; t < kp; t += 1024) {
    int p = base + t;
    if (p < 1024) mainG[(size_t)seg * 1024 + p] = s[t];
  }
  __syncthreads();
  if (tid == 0) {
    int nb = base + kp;
    mcount[seg] = (u32)(nb > 1024 ? 1024 : nb);
  }
}

// per-image: global cut from truncated per-level histograms, then histogram
// RANK-SORT: count per bucket -> suffix-scan bases -> scatter into bucket
// segments -> exact in-bucket rank -> permute in place. Decode inline.
__global__ __launch_bounds__(1024) void k_gsel(const u32* __restrict__ histG,
                                               const u64* __restrict__ mainG,
                                               const u32* __restrict__ mcount,
                                               const float4* __restrict__ priors,
                                               const float4* __restrict__ reg,
                                               float4* __restrict__ boxesG,
                                               int* __restrict__ clsG,
                                               float* __restrict__ scoreG) {
  int img = blockIdx.x;
  int tid = threadIdx.x, wid = tid >> 6, lane = tid & 63;
  __shared__ u32 H[HBUCKETS];     // merged hist; then scan pong; then subhist
  __shared__ u32 cntb[HBUCKETS];
  __shared__ u32 Sarr[HBUCKETS];  // inclusive suffix sums
  __shared__ u32 cnt2[HBUCKETS];
  __shared__ u64 sel[CAPSEL];     // 36864 B
  __shared__ int lcx[NLV], lcy[NLV];
  __shared__ int sh_gx, sh_gy, sh_cC, sh_cand, sh_sgx;
  if (tid == 0) { sh_cC = 0; sh_cand = 0; sh_sgx = -1; }
  if (wid < NLV) {
    int cx, cy;
    wave_find_cut(histG + (size_t)(img * NLV + wid) * HBUCKETS, c_klv[wid], lane, cx, cy);
    if (lane == 0) { lcx[wid] = cx; lcy[wid] = cy; }
  }
  __syncthreads();
  for (int b = tid; b < HBUCKETS; b += 1024) {
    u32 acc = 0;
#pragma unroll
    for (int l = 0; l < NLV; ++l) {
      u32 h = histG[(size_t)(img * NLV + l) * HBUCKETS + b];
      int cx = lcx[l];
      if (cx < 0 || b > cx) acc += h;
      else if (b == cx) acc += (u32)lcy[l];
    }
    H[b] = acc;
    cntb[b] = 0;
    cnt2[b] = 0;
  }
  __syncthreads();
  if (wid == 0) {
    int gx, gy;
    wave_find_cut(H, NPRE, lane, gx, gy);
    if (lane == 0) { sh_gx = gx; sh_gy = gy; }
  }
  __syncthreads();
  int gx = sh_gx, gy = sh_gy;
  int mcap[NLV];
#pragma unroll
  for (int l = 0; l < NLV; ++l) { int c = (int)mcount[img * NLV + l]; mcap[l] = c > 1024 ? 1024 : c; }
  // count pass
  for (int l = 0; l < NLV; ++l)
    for (int t = tid; t < mcap[l]; t += 1024) {
      u64 key = mainG[(size_t)(img * NLV + l) * 1024 + t];
      int b = score_bucket((u32)(key >> 32));
      if (gx < 0 || b > gx) atomicAdd(&cntb[b], 1u);
      else if (b == gx) atomicAdd(&sh_cC, 1);
    }
  __syncthreads();
  // inclusive suffix scan cntb -> Sarr (ping-pong with H; 10 steps)
  for (int b = tid; b < HBUCKETS; b += 1024) Sarr[b] = cntb[b];
  __syncthreads();
  {
    u32* A = Sarr; u32* B = H;
    for (int o = 1; o < HBUCKETS; o <<= 1) {
      for (int b = tid; b < HBUCKETS; b += 1024)
        B[b] = A[b] + ((b + o < HBUCKETS) ? A[b + o] : 0u);
      __syncthreads();
      u32* tmp = A; A = B; B = tmp;
    }
  }
  int cA = (int)Sarr[0];
  int cC = sh_cC;
  int cand = (gx >= 0) ? cC : 0;
  int sgx = -1;
  if (gx >= 0 && cA + cC > CAPSEL) {
    // sub-refine cut bucket by next 10 mantissa bits (measure-zero branch)
    for (int b = tid; b < HBUCKETS; b += 1024) H[b] = 0;
    __syncthreads();
    for (int l = 0; l < NLV; ++l)
      for (int t = tid; t < mcap[l]; t += 1024) {
        u64 key = mainG[(size_t)(img * NLV + l) * 1024 + t];
        u32 bits = (u32)(key >> 32);
        if (score_bucket(bits) == gx) atomicAdd(&H[(bits >> 6) & 1023], 1u);
      }
    __syncthreads();
    if (wid == 0) {
      int a1, a2;
      wave_find_cut(H, gy, lane, a1, a2);
      if (lane == 0) sh_sgx = a1;
    }
    __syncthreads();
    sgx = sh_sgx;
    if (sgx >= 0) {
      for (int s2 = tid; s2 < HBUCKETS; s2 += 1024)
        if (s2 >= sgx) { u32 v = H[s2]; if (v) atomicAdd(&sh_cand, (int)v); }
      __syncthreads();
      cand = sh_cand;
    }
    if (cA + cand > CAPSEL) cand = CAPSEL - cA;  // memory-safety clamp
  }
  __syncthreads();
  // scatter pass
  for (int l = 0; l < NLV; ++l)
    for (int t = tid; t < mcap[l]; t += 1024) {
      u64 key = mainG[(size_t)(img * NLV + l) * 1024 + t];
      u32 bits = (u32)(key >> 32);
      int b = score_bucket(bits);
      bool inc = false; int segbase = 0, seglen = 0;
      if (gx < 0 || b > gx) {
        inc = true; segbase = (int)(Sarr[b] - cntb[b]); seglen = (int)cntb[b];
      } else if (b == gx) {
        inc = (sgx < 0) || ((int)((bits >> 6) & 1023) >= sgx);
        segbase = (int)Sarr[b]; seglen = cand;
      }
      if (inc) {
        int slot = (int)atomicAdd(&cnt2[b], 1u);
        if (slot < seglen) sel[segbase + slot] = key;
      }
    }
  __syncthreads();
  int total = cA + cand;
  // exact in-bucket rank sort (in-place permutation; reads before writes)
  u64 myk[5]; int myp[5];
#pragma unroll
  for (int it = 0; it < 5; ++it) {
    int t = tid + it * 1024;
    myp[it] = -1; myk[it] = 0;
    if (t < total) {
      u64 key = sel[t];
      u32 bits = (u32)(key >> 32);
      int b = score_bucket(bits);
      int segbase, seglen;
      if (gx >= 0 && b == gx) { segbase = (int)Sarr[b]; seglen = cand; }
      else { segbase = (int)(Sarr[b] - cntb[b]); seglen = (int)cntb[b]; }
      int r = 0;
      for (int u = 0; u < seglen; ++u) r += (sel[segbase + u] > key) ? 1 : 0;
      myk[it] = key; myp[it] = segbase + r;
    }
  }
  __syncthreads();
#pragma unroll
  for (int it = 0; it < 5; ++it) if (myp[it] >= 0) sel[myp[it]] = myk[it];
  __syncthreads();
  // decode
  for (int t = tid; t < NPRE; t += 1024) {
    u64 key = (t < total) ? sel[t] : 0ULL;
    float4 bx = make_float4(0.f, 0.f, 0.f, 0.f);
    int c = -1;
    float sc = 0.f;
    if (key != 0ULL) {
      sc = __uint_as_float((u32)(key >> 32));
      u32 flat = 0xFFFFFFFFu - (u32)(key & 0xFFFFFFFFULL);
      int a = (int)(flat / NCLS);
      c = (int)(flat % NCLS);
      float4 p = priors[a];
      float4 r = reg[(size_t)img * A_TOTAL + a];
      float cx = p.x + (r.x * 0.1f) * p.z;
      float cy = p.y + (r.y * 0.1f) * p.w;
      float w = p.z * expf(r.z * 0.2f);
      float h = p.w * expf(r.w * 0.2f);
      bx.x = fminf(fmaxf(cx - w * 0.5f, 0.f), 512.f);
      bx.y = fminf(fmaxf(cy - h * 0.5f, 0.f), 512.f);
      bx.z = fminf(fmaxf(cx + w * 0.5f, 0.f), 512.f);
      bx.w = fminf(fmaxf(cy + h * 0.5f, 0.f), 512.f);
    }
    boxesG[(size_t)img * NPRE + t] = bx;
    clsG[(size_t)img * NPRE + t] = c;
    scoreG[(size_t)img * NPRE + t] = sc;
  }
}

// suppression bitmask: row i, bit j set iff j>i, same class, IoU>0.45
__global__ __launch_bounds__(256) void k_mask(const float4* __restrict__ boxesG,
                                              const int* __restrict__ clsG,
                                              u64* __restrict__ maskG) {
  __shared__ float4 lb[NPRE];
  __shared__ int lc[NPRE];
  int img = blockIdx.x / 500;
  int rb = (blockIdx.x % 500) * 4;
  for (int t = threadIdx.x; t < NPRE; t += 256) {
    lb[t] = boxesG[(size_t)img * NPRE + t];
    lc[t] = clsG[(size_t)img * NPRE + t];
  }
  __syncthreads();
  int w = threadIdx.x >> 6, lane = threadIdx.x & 63;
  int i = rb + w;
  float4 bi = lb[i];
  int ci = lc[i];
  float ai = (bi.z - bi.x) * (bi.w - bi.y);
  u64* mrow = maskG + ((size_t)img * NPRE + i) * 32;
  for (int ch = 0; ch < 32; ++ch) {
    int j = ch * 64 + lane;
    bool pred = false;
    if (j < NPRE && j > i) {
      if (lc[j] == ci) {
        float4 bj = lb[j];
        float xx1 = fmaxf(bi.x, bj.x), yy1 = fmaxf(bi.y, bj.y);
        float xx2 = fminf(bi.z, bj.z), yy2 = fminf(bi.w, bj.w);
        float ww = fmaxf(xx2 - xx1, 0.f), hh = fmaxf(yy2 - yy1, 0.f);
        float inter = ww * hh;
        float aj = (bj.z - bj.x) * (bj.w - bj.y);
        float iou = inter / fmaxf(ai + aj - inter, 1e-6f);
        pred = iou > 0.45f;
      }
    }
    u64 word = __ballot(pred);
    if (lane == 0) mrow[ch] = word;
  }
}

// greedy scan with early exit at 200 kept, fused with final gather.
__global__ __launch_bounds__(256) void k_scanfinal(const u64* __restrict__ maskG,
                                                   const float4* __restrict__ boxesG,
                                                   const int* __restrict__ clsG,
                                                   const float* __restrict__ scoreG,
                                                   float* __restrict__ out) {
  int img = blockIdx.x;
  int tid = threadIdx.x;
  __shared__ u64 sh_remv[32];
  __shared__ u32 keptList[216];
  __shared__ int sh_cnt, sh_done;
  __shared__ int kpref[257];
  __shared__ unsigned short S[NPRE];
  if (tid == 0) { sh_cnt = 0; sh_done = 0; }
  __syncthreads();
  if (tid < 64) {
    int lane = tid;
    int wl = lane & 31;
    const u64* M = maskG + (size_t)img * NPRE * 32;
    u64 remv = 0;
    u64 cur[16], nxt[16];
    int cnt = 0;
#pragma unroll
    for (int r = 0; r < 16; ++r) cur[r] = M[(size_t)r * 32 + wl];
    int t = 0;
    for (; t < 125; ++t) {
      if (t < 124) {
#pragma unroll
        for (int r = 0; r < 16; ++r) nxt[r] = M[(size_t)((t + 1) * 16 + r) * 32 + wl];
      }
#pragma unroll
      for (int r = 0; r < 16; ++r) {
        int i = t * 16 + r;
        u64 rm = shfl_u64(remv, i >> 6);
        if (!((rm >> (i & 63)) & 1ULL)) {
          remv |= cur[r];
          if (lane == 0 && cnt < 216) keptList[cnt] = (u32)i;
          ++cnt;
        }
      }
#pragma unroll
      for (int r = 0; r < 16; ++r) cur[r] = nxt[r];
      if (cnt >= 200) { ++t; break; }
    }
    if (lane == 0) sh_cnt = cnt < 216 ? cnt : 216;
    if (t >= 125) {
      if (lane == 0) sh_done = 1;
      if (lane < 32) sh_remv[lane] = remv;
    }
  }
  __syncthreads();
  int nK = sh_cnt;
  if (sh_done && nK < 200) {
    int base = tid * 8;
    bool sb[8];
    int scnt = 0;
#pragma unroll
    for (int e = 0; e < 8; ++e) {
      int i = base + e;
      bool sup = (i < NPRE) && ((sh_remv[i >> 6] >> (i & 63)) & 1ULL);
      sb[e] = sup;
      scnt += sup ? 1 : 0;
    }
    kpref[tid + 1] = scnt;
    if (tid == 0) kpref[0] = 0;
    __syncthreads();
    if (tid == 0) {
      int acc = 0;
      for (int t = 1; t <= 256; ++t) { acc += kpref[t]; kpref[t] = acc; }
    }
    __syncthreads();
    int sp = kpref[tid];
#pragma unroll
    for (int e = 0; e < 8; ++e) {
      int i = base + e;
      if (i < NPRE && sb[e]) S[sp++] = (unsigned short)i;
    }
    __syncthreads();
    if (tid < 200) {
      float fv = 0.f;
      float4 fb = make_float4(0.f, 0.f, 0.f, 0.f);
      int fc;
      if (tid < nK) {
        int idx = (int)keptList[tid];
        fv = scoreG[(size_t)img * NPRE + idx];
        fb = boxesG[(size_t)img * NPRE + idx];
        fc = clsG[(size_t)img * NPRE + idx];
      } else {
        int idx = S[tid - nK];
        fc = clsG[(size_t)img * NPRE + idx];
      }
      float* fbo = out + (size_t)img * 800 + tid * 4;
      fbo[0] = fb.x; fbo[1] = fb.y; fbo[2] = fb.z; fbo[3] = fb.w;
      out[3200 + (size_t)img * 200 + tid] = fv;
      out[4000 + (size_t)img * 200 + tid] = (float)fc;
    }
  } else {
    if (tid < 200) {
      int idx = (int)keptList[tid];
      float fv = scoreG[(size_t)img * NPRE + idx];
      float4 fb = boxesG[(size_t)img * NPRE + idx];
      int fc = clsG[(size_t)img * NPRE + idx];
      float* fbo = out + (size_t)img * 800 + tid * 4;
      fbo[0] = fb.x; fbo[1] = fb.y; fbo[2] = fb.z; fbo[3] = fb.w;
      out[3200 + (size_t)img * 200 + tid] = fv;
      out[4000 + (size_t)img * 200 + tid] = (float)fc;
    }
  }
}

extern "C" void kernel_launch(void* const* d_in, const int* in_sizes, int n_in,
                              void* d_out, int out_size, void* d_ws, size_t ws_size,
                              hipStream_t stream) {
  const float* logits = (const float*)d_in[0];
  const float4* reg = (const float4*)d_in[1];
  const float4* priors = (const float4*)d_in[2];
  char* ws = (char*)d_ws;
  u32* hist = (u32*)(ws + WS_HIST);
  u32* mcount = (u32*)(ws + WS_MCOUNT);
  u32* bcount = (u32*)(ws + WS_BCOUNT);
  u32* pcount = (u32*)(ws + WS_PCOUNT);
  u64* mainL = (u64*)(ws + WS_MAIN);
  u64* bndL = (u64*)(ws + WS_BND);
  float4* boxes = (float4*)(ws + WS_BOXES);
  int* cls = (int*)(ws + WS_CLS);
  float* score = (float*)(ws + WS_SCORE);
  u64* mask = (u64*)(ws + WS_MASK);
  u64* pool = (u64*)(ws + WS_POOL);

  size_t avail = ws_size > (size_t)WS_POOL ? ws_size - (size_t)WS_POOL : 0;
  int cap = (int)(avail / ((size_t)NBLK_F * 8));
  if (cap > POOL_CAP_MAX) cap = POOL_CAP_MAX;

  k_zero<<<(NZERO_W + 255) / 256, 256, 0, stream>>>((u32*)d_ws);
  k_fused<<<NBLK_F, FT, 0, stream>>>(logits, hist, pool, pcount, cap);
  k_filter<<<NBLK_F, FT, 0, stream>>>(logits, pool, pcount, hist, cap,
                                      mainL, mcount, bndL, bcount);
  k_refine<<<28, 1024, 0, stream>>>(hist, bndL, bcount, mainL, mcount);
  k_gsel<<<NIMG, 1024, 0, stream>>>(hist, mainL, mcount, priors, reg, boxes, cls, score);
  k_mask<<<NIMG * 500, 256, 0, stream>>>(boxes, cls, mask);
  k_scanfinal<<<NIMG, 256, 0, stream>>>(mask, boxes, cls, score, (float*)d_out);
}